// Round 1
// 740.813 us; speedup vs baseline: 1.1991x; 1.1991x over previous
//
#include <hip/hip_runtime.h>
#include <cstdint>
#include <cstddef>

// Problem shape (fixed by reference): B=8, S=2048, D=1024, D_FF=1024
#define BB 8
#define SS 2048
#define DD 1024

typedef unsigned short bf16_t;                                  // raw bf16 bits
typedef __attribute__((ext_vector_type(8))) short bf16x8;       // MFMA A/B frag (4 VGPRs)
typedef __attribute__((ext_vector_type(4))) float f32x4;        // MFMA C/D frag
typedef __attribute__((ext_vector_type(4))) short short4v;

#define EPI_BF16   0   // C = bf16(acc + bias), optional ReLU
#define EPI_SCORES 1   // C = mask ? acc*scale : -1e9  (f32)
#define EPI_RESID  2   // C = acc + bias + resid       (f32, same-element RMW safe)

__device__ __forceinline__ bf16_t f2bf(float f) {
  union { float f; unsigned u; } v; v.f = f;
  unsigned r = v.u + 0x7FFFu + ((v.u >> 16) & 1u);   // RNE
  return (bf16_t)(r >> 16);
}

// async global->LDS, 16B per lane. LDS dst must be wave-uniform base + lane*16.
__device__ __forceinline__ void async_copy16(const void* g, void* l) {
  auto gp = reinterpret_cast<unsigned int __attribute__((address_space(1)))*>(
      reinterpret_cast<uintptr_t>(g));
  auto lp = reinterpret_cast<unsigned int __attribute__((address_space(3)))*>(
      reinterpret_cast<uintptr_t>(l));
  __builtin_amdgcn_global_load_lds(gp, lp, 16, 0, 0);
}

// ---------------------------------------------------------------------------
// 256x256 8-phase NT GEMM: C[M,N] = A[M,K] * BT[N,K]^T, bf16 in, f32 acc.
// BK=64, 512 threads (8 waves, 2x4), per-wave 128x64 out, 16x16x32 MFMA.
// LDS 128 KiB: [2 dbuf][ A: 2 mh-halves 128x64 | B: 2 nh-halves 128x64 ].
// Swizzle: 16B-slot p holds logical slot p^(row&7)  (involution; applied on
// the global SOURCE address in staging and on the ds_read address — rule 21).
// Schedule per K-tile t (4 phases = 4 C-quadrants (mh,nh)):
//   p1 (0,0): stage (t+1).A-mh1 -> dbuf^1
//   p2 (0,1): stage (t+1).B-nh1 -> dbuf^1
//   p3 (1,0): stage (t+2).A-mh0 -> dbuf   (region dead after p2)
//   p4 (1,1): stage (t+2).B-nh0 -> dbuf   (region dead after p3); vmcnt(4)
// vmcnt(4) = 2 half-tiles (4 loads/thread) in flight; drains tile t+1 fully.
// Raw s_barrier everywhere (no implicit vmcnt(0) drain).
// ---------------------------------------------------------------------------
#define MM(i, j, Af, Bf) \
  acc[i][j] = __builtin_amdgcn_mfma_f32_16x16x32_bf16(Af, Bf, acc[i][j], 0, 0, 0)

#define PHASE(D, MH, NH, STAGE_STMT, TAIL_STMT)                                   \
  do {                                                                            \
    const char* Ah_ = ldsc + (D) * 65536 + (MH) * 16384;                          \
    const char* Bh_ = ldsc + (D) * 65536 + 32768 + (NH) * 16384;                  \
    const bf16x8 a0_0 = *(const bf16x8*)(Ah_ + aro +    0 + s0);                  \
    const bf16x8 a1_0 = *(const bf16x8*)(Ah_ + aro + 2048 + s0);                  \
    const bf16x8 a2_0 = *(const bf16x8*)(Ah_ + aro + 4096 + s0);                  \
    const bf16x8 a3_0 = *(const bf16x8*)(Ah_ + aro + 6144 + s0);                  \
    const bf16x8 a0_1 = *(const bf16x8*)(Ah_ + aro +    0 + s1);                  \
    const bf16x8 a1_1 = *(const bf16x8*)(Ah_ + aro + 2048 + s1);                  \
    const bf16x8 a2_1 = *(const bf16x8*)(Ah_ + aro + 4096 + s1);                  \
    const bf16x8 a3_1 = *(const bf16x8*)(Ah_ + aro + 6144 + s1);                  \
    const bf16x8 b0_0 = *(const bf16x8*)(Bh_ + bro +    0 + s0);                  \
    const bf16x8 b1_0 = *(const bf16x8*)(Bh_ + bro + 2048 + s0);                  \
    const bf16x8 b0_1 = *(const bf16x8*)(Bh_ + bro +    0 + s1);                  \
    const bf16x8 b1_1 = *(const bf16x8*)(Bh_ + bro + 2048 + s1);                  \
    STAGE_STMT;                                                                   \
    __builtin_amdgcn_s_barrier();                                                 \
    asm volatile("s_waitcnt lgkmcnt(0)" ::: "memory");                            \
    __builtin_amdgcn_s_setprio(1);                                                \
    MM((MH)*4+0, (NH)*2+0, a0_0, b0_0);  MM((MH)*4+1, (NH)*2+0, a1_0, b0_0);      \
    MM((MH)*4+2, (NH)*2+0, a2_0, b0_0);  MM((MH)*4+3, (NH)*2+0, a3_0, b0_0);      \
    MM((MH)*4+0, (NH)*2+1, a0_0, b1_0);  MM((MH)*4+1, (NH)*2+1, a1_0, b1_0);      \
    MM((MH)*4+2, (NH)*2+1, a2_0, b1_0);  MM((MH)*4+3, (NH)*2+1, a3_0, b1_0);      \
    MM((MH)*4+0, (NH)*2+0, a0_1, b0_1);  MM((MH)*4+1, (NH)*2+0, a1_1, b0_1);      \
    MM((MH)*4+2, (NH)*2+0, a2_1, b0_1);  MM((MH)*4+3, (NH)*2+0, a3_1, b0_1);      \
    MM((MH)*4+0, (NH)*2+1, a0_1, b1_1);  MM((MH)*4+1, (NH)*2+1, a1_1, b1_1);      \
    MM((MH)*4+2, (NH)*2+1, a2_1, b1_1);  MM((MH)*4+3, (NH)*2+1, a3_1, b1_1);      \
    __builtin_amdgcn_s_setprio(0);                                                \
    TAIL_STMT;                                                                    \
    __builtin_amdgcn_s_barrier();                                                 \
  } while (0)

template <int EPI, bool RELU>
__global__ __launch_bounds__(512, 2)
void gemm256(const bf16_t* __restrict__ A, const bf16_t* __restrict__ BT,
             void* __restrict__ Cv,
             const float* __restrict__ bias,   // [<=ldc] or null
             const float* __restrict__ bias2,  // second-half bias (fused QK) or null
             const float* __restrict__ resid,  // [M,ldc] f32 (EPI_RESID)
             const int* __restrict__ mask,     // per-batch mask (EPI_SCORES)
             int Mt, int Nt, int Z, int nchunk,
             int K, int lda, int ldb, int ldc,
             long long sA, long long sB, long long sC, long long sMask,
             float scale)
{
  __shared__ __align__(16) bf16_t lds_[65536];   // 128 KiB
  char* ldsc = (char*)lds_;

  // ---- XCD swizzle: contiguous idx chunk per XCD ----
  const int b = blockIdx.x;
  const int Cchunk = (Z * Mt * Nt) >> 3;           // grid divisible by 8
  int idx = (b & 7) * Cchunk + (b >> 3);
  const int per_z = Mt * Nt;
  const int z = idx / per_z;  idx -= z * per_z;
  const int per_nc = Mt * nchunk;
  const int nc = idx / per_nc; idx -= nc * per_nc;
  const int mt = idx / nchunk;
  const int nin = idx - mt * nchunk;
  const int m0 = mt * 256;
  const int n0 = (nc * nchunk + nin) * 256;

  const int tid  = threadIdx.x;
  const int wave = tid >> 6;
  const int lane = tid & 63;
  const int wr   = wave >> 2, wc = wave & 3;       // 2 x 4 wave grid
  const int lr   = lane & 15, quad = lane >> 4;

  const bf16_t* Ab = A  + (size_t)z * (size_t)sA;
  const bf16_t* Bb = BT + (size_t)z * (size_t)sB;

  f32x4 acc[8][4];
#pragma unroll
  for (int i = 0; i < 8; ++i)
#pragma unroll
    for (int j = 0; j < 4; ++j)
#pragma unroll
      for (int r = 0; r < 4; ++r) acc[i][j][r] = 0.0f;

  // stage one 128x64 half-tile (16KB): thread covers chunks tid and tid+512.
  // Physical 16B slot p within a row holds logical k-chunk p^(row&7).
  auto stageA = [&](int d, int mh, int kt) {
#pragma unroll
    for (int u = 0; u < 2; ++u) {
      const int c = tid + u * 512;
      const int rl = c >> 3;
      const int grow = mh * 64 + ((rl & 64) << 1) + (rl & 63);   // rows mh*64.. & 128+mh*64..
      const int col = kt + (((c & 7) ^ (rl & 7)) << 3);
      async_copy16(Ab + (size_t)(m0 + grow) * lda + col,
                   ldsc + d * 65536 + mh * 16384 + c * 16);
    }
  };
  auto stageB = [&](int d, int nh, int kt) {
#pragma unroll
    for (int u = 0; u < 2; ++u) {
      const int c = tid + u * 512;
      const int rl = c >> 3;
      const int grow = nh * 32 + ((rl & 96) << 1) + (rl & 31);   // rows wc*64+nh*32..
      const int col = kt + (((c & 7) ^ (rl & 7)) << 3);
      async_copy16(Bb + (size_t)(n0 + grow) * ldb + col,
                   ldsc + d * 65536 + 32768 + nh * 16384 + c * 16);
    }
  };

  // ds_read addressing: logical slot s = ks*4+quad; physical = s^(lr&7)
  const int s0  = ((quad ^ (lr & 7)) << 4);        // ks=0 byte offset in row
  const int s1  = s0 ^ 64;                          // ks=1
  const int aro = (wr * 64 + lr) << 7;              // A local-row byte base
  const int bro = (wc * 32 + lr) << 7;              // B local-row byte base

  const int NT = K >> 6;

  // ---- prologue: tile0 (4 halves) + tile1 (A-mh0, B-nh0) ----
  stageA(0, 0, 0); stageA(0, 1, 0); stageB(0, 0, 0); stageB(0, 1, 0);
  if (NT > 1) {
    stageA(1, 0, 64); stageB(1, 0, 64);
    asm volatile("s_waitcnt vmcnt(4)" ::: "memory");   // tile0 resident
  } else {
    asm volatile("s_waitcnt vmcnt(0)" ::: "memory");
  }
  __builtin_amdgcn_s_barrier();

#pragma unroll 2
  for (int t = 0; t < NT; ++t) {
    const int d  = t & 1;
    const int k1 = (t + 1) << 6;
    const int k2 = (t + 2) << 6;
    PHASE(d, 0, 0, if (t + 1 < NT) stageA(d ^ 1, 1, k1), (void)0);
    PHASE(d, 0, 1, if (t + 1 < NT) stageB(d ^ 1, 1, k1), (void)0);
    PHASE(d, 1, 0, if (t + 2 < NT) stageA(d, 0, k2), (void)0);
    PHASE(d, 1, 1, if (t + 2 < NT) stageB(d, 0, k2),
          if (t + 2 < NT) { asm volatile("s_waitcnt vmcnt(4)" ::: "memory"); }
          else            { asm volatile("s_waitcnt vmcnt(0)" ::: "memory"); });
  }

  // ---- epilogue: C/D layout col = lane&15, row = quad*4 + r ----
#pragma unroll
  for (int i = 0; i < 8; ++i) {
    const int gmb = m0 + wr * 128 + (i >> 2) * 64 + (i & 3) * 16 + quad * 4;
#pragma unroll
    for (int j = 0; j < 4; ++j) {
      const int gn = n0 + wc * 64 + (j >> 1) * 32 + (j & 1) * 16 + lr;
      float bv = 0.0f;
      if constexpr (EPI != EPI_SCORES) {
        // gn>=1024 is block-uniform (256-wide n-tiles, 1024-aligned split)
        bv = (bias2 && gn >= 1024) ? bias2[gn - 1024] : (bias ? bias[gn] : 0.0f);
      }
#pragma unroll
      for (int r = 0; r < 4; ++r) {
        float v = acc[i][j][r];
        const size_t off = (size_t)z * (size_t)sC + (size_t)(gmb + r) * ldc + gn;
        if constexpr (EPI == EPI_BF16) {
          v += bv;
          if (RELU) v = v > 0.0f ? v : 0.0f;
          ((bf16_t*)Cv)[off] = f2bf(v);
        } else if constexpr (EPI == EPI_SCORES) {
          const int mk = mask[(size_t)z * (size_t)sMask + gn];
          ((float*)Cv)[off] = mk ? v * scale : -1e9f;
        } else {
          ((float*)Cv)[off] = v + bv + resid[(size_t)(gmb + r) * ldc + gn];
        }
      }
    }
  }
}

// ---------------------------------------------------------------------------
// LayerNorm over D=1024: one block / row, 256 threads x float4. Output bf16.
// ---------------------------------------------------------------------------
__global__ __launch_bounds__(256)
void ln_kernel(const float* __restrict__ x, const float* __restrict__ g,
               const float* __restrict__ b, bf16_t* __restrict__ out)
{
  const int row  = blockIdx.x;
  const int t    = threadIdx.x;
  const int wave = t >> 6, lane = t & 63;
  const float4 v = ((const float4*)(x + (size_t)row * DD))[t];

  float s = v.x + v.y + v.z + v.w;
#pragma unroll
  for (int o = 32; o > 0; o >>= 1) s += __shfl_down(s, o);
  __shared__ float red1[4], red2[4];
  if (lane == 0) red1[wave] = s;
  __syncthreads();
  const float mu = (red1[0] + red1[1] + red1[2] + red1[3]) * (1.0f / DD);

  const float d0 = v.x - mu, d1 = v.y - mu, d2 = v.z - mu, d3 = v.w - mu;
  float ss = d0 * d0 + d1 * d1 + d2 * d2 + d3 * d3;
#pragma unroll
  for (int o = 32; o > 0; o >>= 1) ss += __shfl_down(ss, o);
  if (lane == 0) red2[wave] = ss;
  __syncthreads();
  const float var = (red2[0] + red2[1] + red2[2] + red2[3]) * (1.0f / DD);
  const float rs  = rsqrtf(var + 1e-5f);

  const float4 gg = ((const float4*)g)[t];
  const float4 bb = ((const float4*)b)[t];
  short4v o;
  o.x = (short)f2bf(d0 * rs * gg.x + bb.x);
  o.y = (short)f2bf(d1 * rs * gg.y + bb.y);
  o.z = (short)f2bf(d2 * rs * gg.z + bb.z);
  o.w = (short)f2bf(d3 * rs * gg.w + bb.w);
  *(short4v*)(out + (size_t)row * DD + t * 4) = o;
}

// ---------------------------------------------------------------------------
// Row softmax over S=2048, dual output: f32 in-place + bf16 copy.
// ---------------------------------------------------------------------------
__global__ __launch_bounds__(256)
void softmax_kernel(float* __restrict__ w, bf16_t* __restrict__ wb)
{
  const size_t rowoff = (size_t)blockIdx.x * SS;
  float* p = w + rowoff;
  const int t = threadIdx.x;
  const int wave = t >> 6, lane = t & 63;
  float4 v0 = ((float4*)p)[t];
  float4 v1 = ((float4*)p)[t + 256];

  float m = fmaxf(fmaxf(fmaxf(v0.x, v0.y), fmaxf(v0.z, v0.w)),
                  fmaxf(fmaxf(v1.x, v1.y), fmaxf(v1.z, v1.w)));
#pragma unroll
  for (int o = 32; o > 0; o >>= 1) m = fmaxf(m, __shfl_down(m, o));
  __shared__ float red1[4], red2[4];
  if (lane == 0) red1[wave] = m;
  __syncthreads();
  m = fmaxf(fmaxf(red1[0], red1[1]), fmaxf(red1[2], red1[3]));

  v0.x = __expf(v0.x - m); v0.y = __expf(v0.y - m);
  v0.z = __expf(v0.z - m); v0.w = __expf(v0.w - m);
  v1.x = __expf(v1.x - m); v1.y = __expf(v1.y - m);
  v1.z = __expf(v1.z - m); v1.w = __expf(v1.w - m);

  float s = v0.x + v0.y + v0.z + v0.w + v1.x + v1.y + v1.z + v1.w;
#pragma unroll
  for (int o = 32; o > 0; o >>= 1) s += __shfl_down(s, o);
  if (lane == 0) red2[wave] = s;
  __syncthreads();
  const float inv = 1.0f / (red2[0] + red2[1] + red2[2] + red2[3]);

  v0.x *= inv; v0.y *= inv; v0.z *= inv; v0.w *= inv;
  v1.x *= inv; v1.y *= inv; v1.z *= inv; v1.w *= inv;
  ((float4*)p)[t] = v0;
  ((float4*)p)[t + 256] = v1;

  short4v o0 = { (short)f2bf(v0.x), (short)f2bf(v0.y), (short)f2bf(v0.z), (short)f2bf(v0.w) };
  short4v o1 = { (short)f2bf(v1.x), (short)f2bf(v1.y), (short)f2bf(v1.z), (short)f2bf(v1.w) };
  *(short4v*)(wb + rowoff + t * 4)         = o0;
  *(short4v*)(wb + rowoff + (t + 256) * 4) = o1;
}

// ---------------------------------------------------------------------------
// Tiled transpose (+convert) to bf16: in [R,C](ldin) -> out [C,R]. block (32,8).
// ---------------------------------------------------------------------------
template <typename ST>
__global__ __launch_bounds__(256)
void transpose_to_bf16(const ST* __restrict__ in, bf16_t* __restrict__ out,
                       int R, int C, int ldin, long long inB, long long outB)
{
  __shared__ float tile[32][33];
  const int tx = threadIdx.x, ty = threadIdx.y;
  const size_t zi = (size_t)blockIdx.z * (size_t)inB;
  const size_t zo = (size_t)blockIdx.z * (size_t)outB;
  const int c0 = blockIdx.x * 32, r0 = blockIdx.y * 32;
#pragma unroll
  for (int k = 0; k < 32; k += 8) {
    ST raw = in[zi + (size_t)(r0 + ty + k) * ldin + (c0 + tx)];
    float v;
    if constexpr (sizeof(ST) == 2) {
      v = __uint_as_float(((unsigned)(unsigned short)raw) << 16);
    } else {
      v = (float)raw;
    }
    tile[ty + k][tx] = v;
  }
  __syncthreads();
#pragma unroll
  for (int k = 0; k < 32; k += 8)
    out[zo + (size_t)(c0 + ty + k) * R + (r0 + tx)] = f2bf(tile[tx][ty + k]);
}

// ---------------------------------------------------------------------------
extern "C" void kernel_launch(void* const* d_in, const int* in_sizes, int n_in,
                              void* d_out, int out_size, void* d_ws, size_t ws_size,
                              hipStream_t stream)
{
  const float* x    = (const float*)d_in[0];
  const int*   mask = (const int*)d_in[1];
  const float* ln1g = (const float*)d_in[2];
  const float* ln1b = (const float*)d_in[3];
  const float* Wq   = (const float*)d_in[4];
  const float* bq   = (const float*)d_in[5];
  const float* Wk   = (const float*)d_in[6];
  const float* bk   = (const float*)d_in[7];
  const float* Wo   = (const float*)d_in[8];
  const float* bo   = (const float*)d_in[9];
  const float* ln2g = (const float*)d_in[10];
  const float* ln2b = (const float*)d_in[11];
  const float* W1   = (const float*)d_in[12];
  const float* b1   = (const float*)d_in[13];
  const float* W2   = (const float*)d_in[14];
  const float* b2   = (const float*)d_in[15];

  float* out  = (float*)d_out;                       // (B,S,D) f32, 64MB
  float* wout = out + (size_t)BB * SS * DD;          // (B,S,S) f32, 128MB

  // ---- workspace layout (~170 MB), plus d_out-region reuse ----
  char* ws = (char*)d_ws;
  size_t off = 0;
  auto alloc = [&](size_t bytes) {
    char* p = ws + off; off += (bytes + 255) & ~(size_t)255; return p;
  };
  bf16_t* WqkT = (bf16_t*)alloc((size_t)2 * DD * DD * 2);   // [2048,1024] = WqT ; WkT
  bf16_t* WoT  = (bf16_t*)alloc((size_t)DD * DD * 2);
  bf16_t* W1T  = (bf16_t*)alloc((size_t)DD * DD * 2);
  bf16_t* W2T  = (bf16_t*)alloc((size_t)DD * DD * 2);
  bf16_t* QKb  = (bf16_t*)alloc((size_t)BB * SS * 2 * DD * 2);  // [16384,2048] bf16, 64MB
  char*   Rwb  = alloc((size_t)64 * 1024 * 1024);               // wbf -> xn2+h
  bf16_t* aV   = (bf16_t*)alloc((size_t)BB * SS * DD * 2);      // 32MB

  bf16_t* wbf = (bf16_t*)Rwb;                      // (B,S,S) bf16, dies after w@V
  bf16_t* xn2 = (bf16_t*)Rwb;                      // (B*S,D) bf16 (after wbf dead)
  bf16_t* h   = (bf16_t*)(Rwb + (size_t)32 * 1024 * 1024);  // (B*S,D_FF) bf16

  // d_out reuse: xn lives in wout region (dead before scores written);
  // KT lives in out region (dead before x2 born); x2 lives in out region.
  bf16_t* xn = (bf16_t*)wout;                      // (B*S,D) bf16, dies step 3
  bf16_t* KT = (bf16_t*)out;                       // (B,D,S) bf16, steps 6-7
  float*  x2 = out;                                // (B*S,D) f32, from step 8

  const dim3 tb(256);
  const dim3 tg(512);
  const dim3 tt(32, 8);
  const long long SD   = (long long)SS * DD;       // 2M elems
  const long long S2   = (long long)SS * SS;       // 4M elems
  const long long QKs  = (long long)SS * 2 * DD;   // per-batch elems in QKb

  // 1. weights -> transposed bf16 [N][K]; Wq,Wk concatenated
  transpose_to_bf16<float><<<dim3(32, 32, 1), tt, 0, stream>>>(Wq, WqkT, DD, DD, DD, 0, 0);
  transpose_to_bf16<float><<<dim3(32, 32, 1), tt, 0, stream>>>(Wk, WqkT + (size_t)DD * DD, DD, DD, DD, 0, 0);
  transpose_to_bf16<float><<<dim3(32, 32, 1), tt, 0, stream>>>(Wo, WoT, DD, DD, DD, 0, 0);
  transpose_to_bf16<float><<<dim3(32, 32, 1), tt, 0, stream>>>(W1, W1T, DD, DD, DD, 0, 0);
  transpose_to_bf16<float><<<dim3(32, 32, 1), tt, 0, stream>>>(W2, W2T, DD, DD, DD, 0, 0);

  // 2. xn = LN1(x)
  ln_kernel<<<dim3(BB * SS), tb, 0, stream>>>(x, ln1g, ln1b, xn);

  // 3. QK = xn @ [Wq|Wk] + [bq|bk]   (bf16, [16384,2048])
  gemm256<EPI_BF16, false><<<dim3(512), tg, 0, stream>>>(
      xn, WqkT, QKb, bq, bk, nullptr, nullptr,
      /*Mt,Nt,Z,nc*/ 64, 8, 1, 8, /*K,lda,ldb,ldc*/ DD, DD, DD, 2 * DD,
      0, 0, 0, 0, 1.0f);

  // 4. scores = Q K^T / 32, masked -> wout (f32). Per-XCD chunk == one batch.
  gemm256<EPI_SCORES, false><<<dim3(512), tg, 0, stream>>>(
      QKb, QKb + DD, wout, nullptr, nullptr, nullptr, mask,
      8, 8, BB, 8, /*K,lda,ldb,ldc*/ DD, 2 * DD, 2 * DD, SS,
      QKs, QKs, S2, SS, 0.03125f);

  // 5. softmax rows -> wout (f32) + wbf (bf16)
  softmax_kernel<<<dim3(BB * SS), tb, 0, stream>>>(wout, wbf);

  // 6. V^T: transpose K (cols 1024..2047 of QKb) per batch -> KT [D,S]
  transpose_to_bf16<bf16_t><<<dim3(32, 64, BB), tt, 0, stream>>>(
      QKb + DD, KT, SS, DD, 2 * DD, QKs, SD);

  // 7. attnV = w @ V   (bf16)
  gemm256<EPI_BF16, false><<<dim3(256), tg, 0, stream>>>(
      wbf, KT, aV, nullptr, nullptr, nullptr, nullptr,
      8, 4, BB, 4, /*K,lda,ldb,ldc*/ SS, SS, SS, DD,
      S2, SD, SD, 0, 1.0f);

  // 8. x2 = x + attnV@Wo + bo  (f32, into out region)
  gemm256<EPI_RESID, false><<<dim3(256), tg, 0, stream>>>(
      aV, WoT, x2, bo, nullptr, x, nullptr,
      64, 4, 1, 4, DD, DD, DD, DD, 0, 0, 0, 0, 1.0f);

  // 9. xn2 = LN2(x2)
  ln_kernel<<<dim3(BB * SS), tb, 0, stream>>>(x2, ln2g, ln2b, xn2);

  // 10. h = relu(xn2@W1 + b1)  (bf16)
  gemm256<EPI_BF16, true><<<dim3(256), tg, 0, stream>>>(
      xn2, W1T, h, b1, nullptr, nullptr, nullptr,
      64, 4, 1, 4, DD, DD, DD, DD, 0, 0, 0, 0, 1.0f);

  // 11. out = x2 + h@W2 + b2  (f32, elementwise RMW of out region)
  gemm256<EPI_RESID, false><<<dim3(256), tg, 0, stream>>>(
      h, W2T, out, b2, nullptr, x2, nullptr,
      64, 4, 1, 4, DD, DD, DD, DD, 0, 0, 0, 0, 1.0f);
}

// Round 2
// 702.080 us; speedup vs baseline: 1.2653x; 1.0552x over previous
//
#include <hip/hip_runtime.h>
#include <cstdint>
#include <cstddef>

// Problem shape (fixed by reference): B=8, S=2048, D=1024, D_FF=1024
#define BB 8
#define SS 2048
#define DD 1024

typedef unsigned short bf16_t;                                  // raw bf16 bits
typedef __attribute__((ext_vector_type(8))) short bf16x8;       // MFMA A/B frag (4 VGPRs)
typedef __attribute__((ext_vector_type(4))) float f32x4;        // MFMA C/D frag
typedef __attribute__((ext_vector_type(4))) short short4v;

#define EPI_BF16   0   // C = bf16(acc + bias), optional ReLU
#define EPI_SCORES 1   // C = mask ? acc*scale : -1e9  (f32)
#define EPI_RESID  2   // C = acc + bias + resid       (f32, same-element RMW safe)

__device__ __forceinline__ bf16_t f2bf(float f) {
  union { float f; unsigned u; } v; v.f = f;
  unsigned r = v.u + 0x7FFFu + ((v.u >> 16) & 1u);   // RNE
  return (bf16_t)(r >> 16);
}

// async global->LDS, 16B per lane. LDS dst must be wave-uniform base + lane*16.
__device__ __forceinline__ void async_copy16(const void* g, void* l) {
  auto gp = reinterpret_cast<unsigned int __attribute__((address_space(1)))*>(
      reinterpret_cast<uintptr_t>(g));
  auto lp = reinterpret_cast<unsigned int __attribute__((address_space(3)))*>(
      reinterpret_cast<uintptr_t>(l));
  __builtin_amdgcn_global_load_lds(gp, lp, 16, 0, 0);
}

// ---------------------------------------------------------------------------
// 256x256 8-phase NT GEMM: C[M,N] = A[M,K] * BT[N,K]^T, bf16 in, f32 acc.
// BK=64, 512 threads (8 waves, 2x4), per-wave 128x64 out, 16x16x32 MFMA.
// LDS 128 KiB: [2 dbuf][ A: 2 mh-halves 128x64 | B: 2 nh-halves 128x64 ].
// Swizzle: 16B-slot p holds logical slot p^(row&7)  (involution; applied on
// the global SOURCE address in staging and on the ds_read address — rule 21).
//
// Fragment-reuse phase order (0,0)->(0,1)->(1,1)->(1,0): 24 ds_read_b128 per
// thread per K-tile (the data minimum), vs 48 for re-read-every-phase.
//   p1 (0,0): read A0(8)+B0(4); stage (t+1).A-mh1 -> dbuf^1
//   p2 (0,1): read B1(4), reuse A0; stage (t+1).B-nh1 -> dbuf^1
//   p3 (1,1): read A1(8), reuse B1; stage (t+2).A-mh0 -> dbuf (dead since p1)
//   p4 (1,0): no reads, reuse A1+B0; stage (t+2).B-nh0 -> dbuf; vmcnt(4)
// vmcnt(4) leaves only tile t+2's 4 loads in flight -> tile t+1 resident.
// Raw s_barrier everywhere (no implicit vmcnt(0) drain).
// ---------------------------------------------------------------------------
#define MM(i, j, Af, Bf) \
  acc[i][j] = __builtin_amdgcn_mfma_f32_16x16x32_bf16(Af, Bf, acc[i][j], 0, 0, 0)

#define LDA8(D, MH)                                                        \
  { const char* Ah_ = ldsc + (D) * 65536 + (MH) * 16384;                   \
    aF[0] = *(const bf16x8*)(Ah_ + aro +    0 + s0);                       \
    aF[1] = *(const bf16x8*)(Ah_ + aro + 2048 + s0);                       \
    aF[2] = *(const bf16x8*)(Ah_ + aro + 4096 + s0);                       \
    aF[3] = *(const bf16x8*)(Ah_ + aro + 6144 + s0);                       \
    aF[4] = *(const bf16x8*)(Ah_ + aro +    0 + s1);                       \
    aF[5] = *(const bf16x8*)(Ah_ + aro + 2048 + s1);                       \
    aF[6] = *(const bf16x8*)(Ah_ + aro + 4096 + s1);                       \
    aF[7] = *(const bf16x8*)(Ah_ + aro + 6144 + s1); }

#define LDB4(D, NH, BF)                                                    \
  { const char* Bh_ = ldsc + (D) * 65536 + 32768 + (NH) * 16384;           \
    BF[0] = *(const bf16x8*)(Bh_ + bro +    0 + s0);                       \
    BF[1] = *(const bf16x8*)(Bh_ + bro + 2048 + s0);                       \
    BF[2] = *(const bf16x8*)(Bh_ + bro +    0 + s1);                       \
    BF[3] = *(const bf16x8*)(Bh_ + bro + 2048 + s1); }

// barrier -> drain LDS reads -> prioritized 16-MFMA cluster (one C-quadrant)
#define MFMA16(MH, NH, BF)                                                 \
  __builtin_amdgcn_s_barrier();                                            \
  asm volatile("s_waitcnt lgkmcnt(0)" ::: "memory");                       \
  __builtin_amdgcn_s_setprio(1);                                           \
  MM((MH)*4+0,(NH)*2+0,aF[0],BF[0]); MM((MH)*4+1,(NH)*2+0,aF[1],BF[0]);    \
  MM((MH)*4+2,(NH)*2+0,aF[2],BF[0]); MM((MH)*4+3,(NH)*2+0,aF[3],BF[0]);    \
  MM((MH)*4+0,(NH)*2+1,aF[0],BF[1]); MM((MH)*4+1,(NH)*2+1,aF[1],BF[1]);    \
  MM((MH)*4+2,(NH)*2+1,aF[2],BF[1]); MM((MH)*4+3,(NH)*2+1,aF[3],BF[1]);    \
  MM((MH)*4+0,(NH)*2+0,aF[4],BF[2]); MM((MH)*4+1,(NH)*2+0,aF[5],BF[2]);    \
  MM((MH)*4+2,(NH)*2+0,aF[6],BF[2]); MM((MH)*4+3,(NH)*2+0,aF[7],BF[2]);    \
  MM((MH)*4+0,(NH)*2+1,aF[4],BF[3]); MM((MH)*4+1,(NH)*2+1,aF[5],BF[3]);    \
  MM((MH)*4+2,(NH)*2+1,aF[6],BF[3]); MM((MH)*4+3,(NH)*2+1,aF[7],BF[3]);    \
  __builtin_amdgcn_s_setprio(0);

template <int EPI, bool RELU>
__global__ __launch_bounds__(512, 2)
void gemm256(const bf16_t* __restrict__ A, const bf16_t* __restrict__ BT,
             void* __restrict__ Cv,
             const float* __restrict__ bias,   // [<=ldc] or null
             const float* __restrict__ bias2,  // second-half bias (fused QK) or null
             const float* __restrict__ resid,  // [M,ldc] f32 (EPI_RESID)
             const int* __restrict__ mask,     // per-batch mask (EPI_SCORES)
             int Mt, int Nt, int Z, int nchunk,
             int K, int lda, int ldb, int ldc,
             long long sA, long long sB, long long sC, long long sMask,
             float scale)
{
  __shared__ __align__(16) bf16_t lds_[65536];   // 128 KiB
  char* ldsc = (char*)lds_;

  // ---- XCD swizzle: contiguous idx chunk per XCD ----
  const int b = blockIdx.x;
  const int Cchunk = (Z * Mt * Nt) >> 3;           // grid divisible by 8
  int idx = (b & 7) * Cchunk + (b >> 3);
  const int per_z = Mt * Nt;
  const int z = idx / per_z;  idx -= z * per_z;
  const int per_nc = Mt * nchunk;
  const int nc = idx / per_nc; idx -= nc * per_nc;
  const int mt = idx / nchunk;
  const int nin = idx - mt * nchunk;
  const int m0 = mt * 256;
  const int n0 = (nc * nchunk + nin) * 256;

  const int tid  = threadIdx.x;
  const int wave = tid >> 6;
  const int lane = tid & 63;
  const int wr   = wave >> 2, wc = wave & 3;       // 2 x 4 wave grid
  const int lr   = lane & 15, quad = lane >> 4;

  const bf16_t* Ab = A  + (size_t)z * (size_t)sA;
  const bf16_t* Bb = BT + (size_t)z * (size_t)sB;

  f32x4 acc[8][4];
#pragma unroll
  for (int i = 0; i < 8; ++i)
#pragma unroll
    for (int j = 0; j < 4; ++j)
#pragma unroll
      for (int r = 0; r < 4; ++r) acc[i][j][r] = 0.0f;

  // stage one 128x64 half-tile (16KB): thread covers chunks tid and tid+512.
  // Physical 16B slot p within a row holds logical k-chunk p^(row&7).
  auto stageA = [&](int d, int mh, int kt) {
#pragma unroll
    for (int u = 0; u < 2; ++u) {
      const int c = tid + u * 512;
      const int rl = c >> 3;
      const int grow = mh * 64 + ((rl & 64) << 1) + (rl & 63);   // rows mh*64.. & 128+mh*64..
      const int col = kt + (((c & 7) ^ (rl & 7)) << 3);
      async_copy16(Ab + (size_t)(m0 + grow) * lda + col,
                   ldsc + d * 65536 + mh * 16384 + c * 16);
    }
  };
  auto stageB = [&](int d, int nh, int kt) {
#pragma unroll
    for (int u = 0; u < 2; ++u) {
      const int c = tid + u * 512;
      const int rl = c >> 3;
      const int grow = nh * 32 + ((rl & 96) << 1) + (rl & 31);   // rows wc*64+nh*32..
      const int col = kt + (((c & 7) ^ (rl & 7)) << 3);
      async_copy16(Bb + (size_t)(n0 + grow) * ldb + col,
                   ldsc + d * 65536 + 32768 + nh * 16384 + c * 16);
    }
  };

  // ds_read addressing: logical slot s = ks*4+quad; physical = s^(lr&7)
  const int s0  = ((quad ^ (lr & 7)) << 4);        // ks=0 byte offset in row
  const int s1  = s0 ^ 64;                          // ks=1
  const int aro = (wr * 64 + lr) << 7;              // A local-row byte base
  const int bro = (wc * 32 + lr) << 7;              // B local-row byte base

  bf16x8 aF[8];          // current A-half fragments (4 rows x 2 ks)
  bf16x8 bF0[4], bF1[4]; // B-half fragment sets (2 cols x 2 ks each)

  const int NT = K >> 6;

  // ---- prologue: tile0 (4 halves) + tile1 (A-mh0, B-nh0) ----
  stageA(0, 0, 0); stageA(0, 1, 0); stageB(0, 0, 0); stageB(0, 1, 0);
  if (NT > 1) {
    stageA(1, 0, 64); stageB(1, 0, 64);
    asm volatile("s_waitcnt vmcnt(4)" ::: "memory");   // tile0 resident
  } else {
    asm volatile("s_waitcnt vmcnt(0)" ::: "memory");
  }
  __builtin_amdgcn_s_barrier();

#pragma unroll 2
  for (int t = 0; t < NT; ++t) {
    const int d  = t & 1;
    const int k1 = (t + 1) << 6;
    const int k2 = (t + 2) << 6;

    // p1: quadrant (0,0) — fresh A-half0 + B-half0
    LDA8(d, 0); LDB4(d, 0, bF0);
    if (t + 1 < NT) stageA(d ^ 1, 1, k1);
    MFMA16(0, 0, bF0);
    __builtin_amdgcn_s_barrier();

    // p2: quadrant (0,1) — reuse A0, fresh B-half1
    LDB4(d, 1, bF1);
    if (t + 1 < NT) stageB(d ^ 1, 1, k1);
    MFMA16(0, 1, bF1);
    __builtin_amdgcn_s_barrier();

    // p3: quadrant (1,1) — fresh A-half1, reuse B1
    LDA8(d, 1);
    if (t + 2 < NT) stageA(d, 0, k2);
    MFMA16(1, 1, bF1);
    __builtin_amdgcn_s_barrier();

    // p4: quadrant (1,0) — reuse A1 + B0, zero ds_reads
    if (t + 2 < NT) stageB(d, 0, k2);
    MFMA16(1, 0, bF0);
    if (t + 2 < NT) { asm volatile("s_waitcnt vmcnt(4)" ::: "memory"); }
    else            { asm volatile("s_waitcnt vmcnt(0)" ::: "memory"); }
    __builtin_amdgcn_s_barrier();
  }

  // ---- epilogue: C/D layout col = lane&15, row = quad*4 + r ----
#pragma unroll
  for (int i = 0; i < 8; ++i) {
    const int gmb = m0 + wr * 128 + (i >> 2) * 64 + (i & 3) * 16 + quad * 4;
#pragma unroll
    for (int j = 0; j < 4; ++j) {
      const int gn = n0 + wc * 64 + (j >> 1) * 32 + (j & 1) * 16 + lr;
      float bv = 0.0f;
      if constexpr (EPI != EPI_SCORES) {
        // gn>=1024 is block-uniform (256-wide n-tiles, 1024-aligned split)
        bv = (bias2 && gn >= 1024) ? bias2[gn - 1024] : (bias ? bias[gn] : 0.0f);
      }
#pragma unroll
      for (int r = 0; r < 4; ++r) {
        float v = acc[i][j][r];
        const size_t off = (size_t)z * (size_t)sC + (size_t)(gmb + r) * ldc + gn;
        if constexpr (EPI == EPI_BF16) {
          v += bv;
          if (RELU) v = v > 0.0f ? v : 0.0f;
          ((bf16_t*)Cv)[off] = f2bf(v);
        } else if constexpr (EPI == EPI_SCORES) {
          const int mk = mask[(size_t)z * (size_t)sMask + gn];
          ((float*)Cv)[off] = mk ? v * scale : -1e9f;
        } else {
          ((float*)Cv)[off] = v + bv + resid[(size_t)(gmb + r) * ldc + gn];
        }
      }
    }
  }
}

// ---------------------------------------------------------------------------
// LayerNorm over D=1024: one block / row, 256 threads x float4. Output bf16.
// ---------------------------------------------------------------------------
__global__ __launch_bounds__(256)
void ln_kernel(const float* __restrict__ x, const float* __restrict__ g,
               const float* __restrict__ b, bf16_t* __restrict__ out)
{
  const int row  = blockIdx.x;
  const int t    = threadIdx.x;
  const int wave = t >> 6, lane = t & 63;
  const float4 v = ((const float4*)(x + (size_t)row * DD))[t];

  float s = v.x + v.y + v.z + v.w;
#pragma unroll
  for (int o = 32; o > 0; o >>= 1) s += __shfl_down(s, o);
  __shared__ float red1[4], red2[4];
  if (lane == 0) red1[wave] = s;
  __syncthreads();
  const float mu = (red1[0] + red1[1] + red1[2] + red1[3]) * (1.0f / DD);

  const float d0 = v.x - mu, d1 = v.y - mu, d2 = v.z - mu, d3 = v.w - mu;
  float ss = d0 * d0 + d1 * d1 + d2 * d2 + d3 * d3;
#pragma unroll
  for (int o = 32; o > 0; o >>= 1) ss += __shfl_down(ss, o);
  if (lane == 0) red2[wave] = ss;
  __syncthreads();
  const float var = (red2[0] + red2[1] + red2[2] + red2[3]) * (1.0f / DD);
  const float rs  = rsqrtf(var + 1e-5f);

  const float4 gg = ((const float4*)g)[t];
  const float4 bb = ((const float4*)b)[t];
  short4v o;
  o.x = (short)f2bf(d0 * rs * gg.x + bb.x);
  o.y = (short)f2bf(d1 * rs * gg.y + bb.y);
  o.z = (short)f2bf(d2 * rs * gg.z + bb.z);
  o.w = (short)f2bf(d3 * rs * gg.w + bb.w);
  *(short4v*)(out + (size_t)row * DD + t * 4) = o;
}

// ---------------------------------------------------------------------------
// Row softmax over S=2048, dual output: f32 in-place + bf16 copy.
// ---------------------------------------------------------------------------
__global__ __launch_bounds__(256)
void softmax_kernel(float* __restrict__ w, bf16_t* __restrict__ wb)
{
  const size_t rowoff = (size_t)blockIdx.x * SS;
  float* p = w + rowoff;
  const int t = threadIdx.x;
  const int wave = t >> 6, lane = t & 63;
  float4 v0 = ((float4*)p)[t];
  float4 v1 = ((float4*)p)[t + 256];

  float m = fmaxf(fmaxf(fmaxf(v0.x, v0.y), fmaxf(v0.z, v0.w)),
                  fmaxf(fmaxf(v1.x, v1.y), fmaxf(v1.z, v1.w)));
#pragma unroll
  for (int o = 32; o > 0; o >>= 1) m = fmaxf(m, __shfl_down(m, o));
  __shared__ float red1[4], red2[4];
  if (lane == 0) red1[wave] = m;
  __syncthreads();
  m = fmaxf(fmaxf(red1[0], red1[1]), fmaxf(red1[2], red1[3]));

  v0.x = __expf(v0.x - m); v0.y = __expf(v0.y - m);
  v0.z = __expf(v0.z - m); v0.w = __expf(v0.w - m);
  v1.x = __expf(v1.x - m); v1.y = __expf(v1.y - m);
  v1.z = __expf(v1.z - m); v1.w = __expf(v1.w - m);

  float s = v0.x + v0.y + v0.z + v0.w + v1.x + v1.y + v1.z + v1.w;
#pragma unroll
  for (int o = 32; o > 0; o >>= 1) s += __shfl_down(s, o);
  if (lane == 0) red2[wave] = s;
  __syncthreads();
  const float inv = 1.0f / (red2[0] + red2[1] + red2[2] + red2[3]);

  v0.x *= inv; v0.y *= inv; v0.z *= inv; v0.w *= inv;
  v1.x *= inv; v1.y *= inv; v1.z *= inv; v1.w *= inv;
  ((float4*)p)[t] = v0;
  ((float4*)p)[t + 256] = v1;

  short4v o0 = { (short)f2bf(v0.x), (short)f2bf(v0.y), (short)f2bf(v0.z), (short)f2bf(v0.w) };
  short4v o1 = { (short)f2bf(v1.x), (short)f2bf(v1.y), (short)f2bf(v1.z), (short)f2bf(v1.w) };
  *(short4v*)(wb + rowoff + t * 4)         = o0;
  *(short4v*)(wb + rowoff + (t + 256) * 4) = o1;
}

// ---------------------------------------------------------------------------
// Tiled transpose (+convert) to bf16: in [R,C](ldin) -> out [C,R]. block (32,8).
// ---------------------------------------------------------------------------
template <typename ST>
__global__ __launch_bounds__(256)
void transpose_to_bf16(const ST* __restrict__ in, bf16_t* __restrict__ out,
                       int R, int C, int ldin, long long inB, long long outB)
{
  __shared__ float tile[32][33];
  const int tx = threadIdx.x, ty = threadIdx.y;
  const size_t zi = (size_t)blockIdx.z * (size_t)inB;
  const size_t zo = (size_t)blockIdx.z * (size_t)outB;
  const int c0 = blockIdx.x * 32, r0 = blockIdx.y * 32;
#pragma unroll
  for (int k = 0; k < 32; k += 8) {
    ST raw = in[zi + (size_t)(r0 + ty + k) * ldin + (c0 + tx)];
    float v;
    if constexpr (sizeof(ST) == 2) {
      v = __uint_as_float(((unsigned)(unsigned short)raw) << 16);
    } else {
      v = (float)raw;
    }
    tile[ty + k][tx] = v;
  }
  __syncthreads();
#pragma unroll
  for (int k = 0; k < 32; k += 8)
    out[zo + (size_t)(c0 + ty + k) * R + (r0 + tx)] = f2bf(tile[tx][ty + k]);
}

// ---------------------------------------------------------------------------
extern "C" void kernel_launch(void* const* d_in, const int* in_sizes, int n_in,
                              void* d_out, int out_size, void* d_ws, size_t ws_size,
                              hipStream_t stream)
{
  const float* x    = (const float*)d_in[0];
  const int*   mask = (const int*)d_in[1];
  const float* ln1g = (const float*)d_in[2];
  const float* ln1b = (const float*)d_in[3];
  const float* Wq   = (const float*)d_in[4];
  const float* bq   = (const float*)d_in[5];
  const float* Wk   = (const float*)d_in[6];
  const float* bk   = (const float*)d_in[7];
  const float* Wo   = (const float*)d_in[8];
  const float* bo   = (const float*)d_in[9];
  const float* ln2g = (const float*)d_in[10];
  const float* ln2b = (const float*)d_in[11];
  const float* W1   = (const float*)d_in[12];
  const float* b1   = (const float*)d_in[13];
  const float* W2   = (const float*)d_in[14];
  const float* b2   = (const float*)d_in[15];

  float* out  = (float*)d_out;                       // (B,S,D) f32, 64MB
  float* wout = out + (size_t)BB * SS * DD;          // (B,S,S) f32, 128MB

  // ---- workspace layout (~170 MB), plus d_out-region reuse ----
  char* ws = (char*)d_ws;
  size_t off = 0;
  auto alloc = [&](size_t bytes) {
    char* p = ws + off; off += (bytes + 255) & ~(size_t)255; return p;
  };
  bf16_t* WqkT = (bf16_t*)alloc((size_t)2 * DD * DD * 2);   // [2048,1024] = WqT ; WkT
  bf16_t* WoT  = (bf16_t*)alloc((size_t)DD * DD * 2);
  bf16_t* W1T  = (bf16_t*)alloc((size_t)DD * DD * 2);
  bf16_t* W2T  = (bf16_t*)alloc((size_t)DD * DD * 2);
  bf16_t* QKb  = (bf16_t*)alloc((size_t)BB * SS * 2 * DD * 2);  // [16384,2048] bf16, 64MB
  char*   Rwb  = alloc((size_t)64 * 1024 * 1024);               // wbf -> xn2+h
  bf16_t* aV   = (bf16_t*)alloc((size_t)BB * SS * DD * 2);      // 32MB

  bf16_t* wbf = (bf16_t*)Rwb;                      // (B,S,S) bf16, dies after w@V
  bf16_t* xn2 = (bf16_t*)Rwb;                      // (B*S,D) bf16 (after wbf dead)
  bf16_t* h   = (bf16_t*)(Rwb + (size_t)32 * 1024 * 1024);  // (B*S,D_FF) bf16

  // d_out reuse: xn lives in wout region (dead before scores written);
  // KT lives in out region (dead before x2 born); x2 lives in out region.
  bf16_t* xn = (bf16_t*)wout;                      // (B*S,D) bf16, dies step 3
  bf16_t* KT = (bf16_t*)out;                       // (B,D,S) bf16, steps 6-7
  float*  x2 = out;                                // (B*S,D) f32, from step 8

  const dim3 tb(256);
  const dim3 tg(512);
  const dim3 tt(32, 8);
  const long long SD   = (long long)SS * DD;       // 2M elems
  const long long S2   = (long long)SS * SS;       // 4M elems
  const long long QKs  = (long long)SS * 2 * DD;   // per-batch elems in QKb

  // 1. weights -> transposed bf16 [N][K]; Wq,Wk concatenated
  transpose_to_bf16<float><<<dim3(32, 32, 1), tt, 0, stream>>>(Wq, WqkT, DD, DD, DD, 0, 0);
  transpose_to_bf16<float><<<dim3(32, 32, 1), tt, 0, stream>>>(Wk, WqkT + (size_t)DD * DD, DD, DD, DD, 0, 0);
  transpose_to_bf16<float><<<dim3(32, 32, 1), tt, 0, stream>>>(Wo, WoT, DD, DD, DD, 0, 0);
  transpose_to_bf16<float><<<dim3(32, 32, 1), tt, 0, stream>>>(W1, W1T, DD, DD, DD, 0, 0);
  transpose_to_bf16<float><<<dim3(32, 32, 1), tt, 0, stream>>>(W2, W2T, DD, DD, DD, 0, 0);

  // 2. xn = LN1(x)
  ln_kernel<<<dim3(BB * SS), tb, 0, stream>>>(x, ln1g, ln1b, xn);

  // 3. QK = xn @ [Wq|Wk] + [bq|bk]   (bf16, [16384,2048])
  gemm256<EPI_BF16, false><<<dim3(512), tg, 0, stream>>>(
      xn, WqkT, QKb, bq, bk, nullptr, nullptr,
      /*Mt,Nt,Z,nc*/ 64, 8, 1, 8, /*K,lda,ldb,ldc*/ DD, DD, DD, 2 * DD,
      0, 0, 0, 0, 1.0f);

  // 4. scores = Q K^T / 32, masked -> wout (f32). Per-XCD chunk == one batch.
  gemm256<EPI_SCORES, false><<<dim3(512), tg, 0, stream>>>(
      QKb, QKb + DD, wout, nullptr, nullptr, nullptr, mask,
      8, 8, BB, 8, /*K,lda,ldb,ldc*/ DD, 2 * DD, 2 * DD, SS,
      QKs, QKs, S2, SS, 0.03125f);

  // 5. softmax rows -> wout (f32) + wbf (bf16)
  softmax_kernel<<<dim3(BB * SS), tb, 0, stream>>>(wout, wbf);

  // 6. V^T: transpose K (cols 1024..2047 of QKb) per batch -> KT [D,S]
  transpose_to_bf16<bf16_t><<<dim3(32, 64, BB), tt, 0, stream>>>(
      QKb + DD, KT, SS, DD, 2 * DD, QKs, SD);

  // 7. attnV = w @ V   (bf16)
  gemm256<EPI_BF16, false><<<dim3(256), tg, 0, stream>>>(
      wbf, KT, aV, nullptr, nullptr, nullptr, nullptr,
      8, 4, BB, 4, /*K,lda,ldb,ldc*/ SS, SS, SS, DD,
      S2, SD, SD, 0, 1.0f);

  // 8. x2 = x + attnV@Wo + bo  (f32, into out region)
  gemm256<EPI_RESID, false><<<dim3(256), tg, 0, stream>>>(
      aV, WoT, x2, bo, nullptr, x, nullptr,
      64, 4, 1, 4, DD, DD, DD, DD, 0, 0, 0, 0, 1.0f);

  // 9. xn2 = LN2(x2)
  ln_kernel<<<dim3(BB * SS), tb, 0, stream>>>(x2, ln2g, ln2b, xn2);

  // 10. h = relu(xn2@W1 + b1)  (bf16)
  gemm256<EPI_BF16, true><<<dim3(256), tg, 0, stream>>>(
      xn2, W1T, h, b1, nullptr, nullptr, nullptr,
      64, 4, 1, 4, DD, DD, DD, DD, 0, 0, 0, 0, 1.0f);

  // 11. out = x2 + h@W2 + b2  (f32, elementwise RMW of out region)
  gemm256<EPI_RESID, false><<<dim3(256), tg, 0, stream>>>(
      h, W2T, out, b2, nullptr, x2, nullptr,
      64, 4, 1, 4, DD, DD, DD, DD, 0, 0, 0, 0, 1.0f);
}

// Round 3
// 689.770 us; speedup vs baseline: 1.2879x; 1.0178x over previous
//
#include <hip/hip_runtime.h>
#include <cstdint>
#include <cstddef>

// Problem shape (fixed by reference): B=8, S=2048, D=1024, D_FF=1024
#define BB 8
#define SS 2048
#define DD 1024

typedef unsigned short bf16_t;                                  // raw bf16 bits
typedef __attribute__((ext_vector_type(8))) short bf16x8;       // MFMA A/B frag (4 VGPRs)
typedef __attribute__((ext_vector_type(4))) float f32x4;        // MFMA C/D frag
typedef __attribute__((ext_vector_type(4))) short short4v;

#define EPI_BF16   0   // C = bf16(acc + bias), optional ReLU
#define EPI_SCORES 1   // C = mask ? acc*scale : -1e9  (f32)
#define EPI_RESID  2   // C = acc + bias + resid       (f32, same-element RMW safe)

__device__ __forceinline__ bf16_t f2bf(float f) {
  union { float f; unsigned u; } v; v.f = f;
  unsigned r = v.u + 0x7FFFu + ((v.u >> 16) & 1u);   // RNE
  return (bf16_t)(r >> 16);
}

// async global->LDS, 16B per lane. LDS dst must be wave-uniform base + lane*16.
__device__ __forceinline__ void async_copy16(const void* g, void* l) {
  auto gp = reinterpret_cast<unsigned int __attribute__((address_space(1)))*>(
      reinterpret_cast<uintptr_t>(g));
  auto lp = reinterpret_cast<unsigned int __attribute__((address_space(3)))*>(
      reinterpret_cast<uintptr_t>(l));
  __builtin_amdgcn_global_load_lds(gp, lp, 16, 0, 0);
}

// ---------------------------------------------------------------------------
// 256x256 NT GEMM: C[M,N] = A[M,K] * BT[N,K]^T, bf16 in, f32 acc.
// BK=64, 512 threads (8 waves, 2x4), per-wave 128x64 out, 16x16x32 MFMA.
// LDS 128 KiB: [2 dbuf][ A: 2 mh-halves 128x64 | B: 2 nh-halves 128x64 ].
// Swizzle: 16B-slot p holds logical slot p^(row&7)  (involution; applied on
// the global SOURCE address in staging and on the ds_read address — rule 21).
//
// SINGLE barrier per phase: [reads + stage-issue] bar [setprio; 16 MFMA].
// Cross-wave overlap: while wave X runs its MFMA cluster (post-bar), wave Y
// already issues next-phase ds_reads/stages (pre-next-bar). Hazards:
//  - stale-read: reads of tile t covered by vmcnt(4)+bar at (t-1).p4, which
//    drains ALL of tile t's 4 half-tiles (12 outstanding -> 4).
//  - overwrite: stage at phase p targets a region whose last reader finished
//    its reads before its phase-(p-2) MFMA, sequenced before its arrival at
//    the barrier the staging wave must pass. Max skew = 1 phase.
// No explicit lgkmcnt(0): plain-pointer ds_reads let the compiler emit
// counted lgkm waits interleaved with the MFMA cluster.
// Fragment-reuse order (0,0)->(0,1)->(1,1)->(1,0): 24 ds_read_b128/tile.
// ---------------------------------------------------------------------------
#define MM(i, j, Af, Bf) \
  acc[i][j] = __builtin_amdgcn_mfma_f32_16x16x32_bf16(Af, Bf, acc[i][j], 0, 0, 0)

#define LDA8(D, MH)                                                        \
  { const char* Ah_ = ldsc + (D) * 65536 + (MH) * 16384;                   \
    aF[0] = *(const bf16x8*)(Ah_ + aro +    0 + s0);                       \
    aF[1] = *(const bf16x8*)(Ah_ + aro + 2048 + s0);                       \
    aF[2] = *(const bf16x8*)(Ah_ + aro + 4096 + s0);                       \
    aF[3] = *(const bf16x8*)(Ah_ + aro + 6144 + s0);                       \
    aF[4] = *(const bf16x8*)(Ah_ + aro +    0 + s1);                       \
    aF[5] = *(const bf16x8*)(Ah_ + aro + 2048 + s1);                       \
    aF[6] = *(const bf16x8*)(Ah_ + aro + 4096 + s1);                       \
    aF[7] = *(const bf16x8*)(Ah_ + aro + 6144 + s1); }

#define LDB4(D, NH, BF)                                                    \
  { const char* Bh_ = ldsc + (D) * 65536 + 32768 + (NH) * 16384;           \
    BF[0] = *(const bf16x8*)(Bh_ + bro +    0 + s0);                       \
    BF[1] = *(const bf16x8*)(Bh_ + bro + 2048 + s0);                       \
    BF[2] = *(const bf16x8*)(Bh_ + bro +    0 + s1);                       \
    BF[3] = *(const bf16x8*)(Bh_ + bro + 2048 + s1); }

// prioritized 16-MFMA cluster (one C-quadrant); compiler inserts lgkm waits
#define MFMA16(MH, NH, BF)                                                 \
  __builtin_amdgcn_s_setprio(1);                                           \
  MM((MH)*4+0,(NH)*2+0,aF[0],BF[0]); MM((MH)*4+1,(NH)*2+0,aF[1],BF[0]);    \
  MM((MH)*4+2,(NH)*2+0,aF[2],BF[0]); MM((MH)*4+3,(NH)*2+0,aF[3],BF[0]);    \
  MM((MH)*4+0,(NH)*2+1,aF[0],BF[1]); MM((MH)*4+1,(NH)*2+1,aF[1],BF[1]);    \
  MM((MH)*4+2,(NH)*2+1,aF[2],BF[1]); MM((MH)*4+3,(NH)*2+1,aF[3],BF[1]);    \
  MM((MH)*4+0,(NH)*2+0,aF[4],BF[2]); MM((MH)*4+1,(NH)*2+0,aF[5],BF[2]);    \
  MM((MH)*4+2,(NH)*2+0,aF[6],BF[2]); MM((MH)*4+3,(NH)*2+0,aF[7],BF[2]);    \
  MM((MH)*4+0,(NH)*2+1,aF[4],BF[3]); MM((MH)*4+1,(NH)*2+1,aF[5],BF[3]);    \
  MM((MH)*4+2,(NH)*2+1,aF[6],BF[3]); MM((MH)*4+3,(NH)*2+1,aF[7],BF[3]);    \
  __builtin_amdgcn_s_setprio(0);

template <int EPI, bool RELU>
__global__ __launch_bounds__(512, 2)
void gemm256(const bf16_t* __restrict__ A, const bf16_t* __restrict__ BT,
             void* __restrict__ Cv,
             const float* __restrict__ bias,   // [<=ldc] or null
             const float* __restrict__ bias2,  // second-half bias (fused QK) or null
             const float* __restrict__ resid,  // [M,ldc] f32 (EPI_RESID)
             const int* __restrict__ mask,     // per-batch mask (EPI_SCORES)
             int Mt, int Nt, int Z, int nchunk,
             int K, int lda, int ldb, int ldc,
             long long sA, long long sB, long long sC, long long sMask,
             float scale)
{
  __shared__ __align__(16) bf16_t lds_[65536];   // 128 KiB
  char* ldsc = (char*)lds_;

  // ---- XCD swizzle: contiguous idx chunk per XCD ----
  const int b = blockIdx.x;
  const int Cchunk = (Z * Mt * Nt) >> 3;           // grid divisible by 8
  int idx = (b & 7) * Cchunk + (b >> 3);
  const int per_z = Mt * Nt;
  const int z = idx / per_z;  idx -= z * per_z;
  const int per_nc = Mt * nchunk;
  const int nc = idx / per_nc; idx -= nc * per_nc;
  const int mt = idx / nchunk;
  const int nin = idx - mt * nchunk;
  const int m0 = mt * 256;
  const int n0 = (nc * nchunk + nin) * 256;

  const int tid  = threadIdx.x;
  const int wave = tid >> 6;
  const int lane = tid & 63;
  const int wr   = wave >> 2, wc = wave & 3;       // 2 x 4 wave grid
  const int lr   = lane & 15, quad = lane >> 4;

  const bf16_t* Ab = A  + (size_t)z * (size_t)sA;
  const bf16_t* Bb = BT + (size_t)z * (size_t)sB;

  f32x4 acc[8][4];
#pragma unroll
  for (int i = 0; i < 8; ++i)
#pragma unroll
    for (int j = 0; j < 4; ++j)
#pragma unroll
      for (int r = 0; r < 4; ++r) acc[i][j][r] = 0.0f;

  // ---- staging geometry, hoisted: per-thread base pointers computed once;
  // per stage call = base + uniform elem offset (mh*64*ld + kt), no 64b mul.
  // Physical 16B slot p within a row holds logical k-chunk p^(row&7).
  const bf16_t* gA[2]; const bf16_t* gB[2]; char* lA[2]; char* lB[2];
#pragma unroll
  for (int u = 0; u < 2; ++u) {
    const int c = tid + u * 512;
    const int rl = c >> 3;
    const int csw = (((c & 7) ^ (rl & 7)) << 3);                 // swizzled k-elems
    const int rowA = ((rl & 64) << 1) + (rl & 63);               // rows 0..63,128..191
    const int rowB = ((rl & 96) << 1) + (rl & 31);               // rows 0..31,64..95,...
    gA[u] = Ab + (size_t)(m0 + rowA) * lda + csw;
    gB[u] = Bb + (size_t)(n0 + rowB) * ldb + csw;
    lA[u] = ldsc + c * 16;
    lB[u] = ldsc + 32768 + c * 16;
  }
  const int ldA64 = lda << 6, ldB64 = ldb << 5;    // A: +64 rows; B: +32 rows per nh

  auto stageA = [&](int d, int mh, int kt) {
    const int go = mh * ldA64 + kt;
    const int lo = d * 65536 + mh * 16384;
#pragma unroll
    for (int u = 0; u < 2; ++u) async_copy16(gA[u] + go, lA[u] + lo);
  };
  auto stageB = [&](int d, int nh, int kt) {
    const int go = nh * ldB64 + kt;
    const int lo = d * 65536 + nh * 16384;
#pragma unroll
    for (int u = 0; u < 2; ++u) async_copy16(gB[u] + go, lB[u] + lo);
  };

  // ds_read addressing: logical slot s = ks*4+quad; physical = s^(lr&7)
  const int s0  = ((quad ^ (lr & 7)) << 4);        // ks=0 byte offset in row
  const int s1  = s0 ^ 64;                          // ks=1
  const int aro = (wr * 64 + lr) << 7;              // A local-row byte base
  const int bro = (wc * 32 + lr) << 7;              // B local-row byte base

  bf16x8 aF[8];          // current A-half fragments (4 rows x 2 ks)
  bf16x8 bF0[4], bF1[4]; // B-half fragment sets (2 cols x 2 ks each)

  const int NT = K >> 6;

  // ---- prologue: tile0 (4 halves) + tile1 (A-mh0, B-nh0) ----
  stageA(0, 0, 0); stageA(0, 1, 0); stageB(0, 0, 0); stageB(0, 1, 0);
  if (NT > 1) {
    stageA(1, 0, 64); stageB(1, 0, 64);
    asm volatile("s_waitcnt vmcnt(4)" ::: "memory");   // tile0 resident
  } else {
    asm volatile("s_waitcnt vmcnt(0)" ::: "memory");
  }
  __builtin_amdgcn_s_barrier();

#pragma unroll 2
  for (int t = 0; t < NT; ++t) {
    const int d  = t & 1;
    const int k1 = (t + 1) << 6;
    const int k2 = (t + 2) << 6;

    // p1: quadrant (0,0) — fresh A-half0 + B-half0; stage t+1.A1
    LDA8(d, 0); LDB4(d, 0, bF0);
    if (t + 1 < NT) stageA(d ^ 1, 1, k1);
    __builtin_amdgcn_s_barrier();
    MFMA16(0, 0, bF0);

    // p2: quadrant (0,1) — reuse A0, fresh B-half1; stage t+1.B1
    LDB4(d, 1, bF1);
    if (t + 1 < NT) stageB(d ^ 1, 1, k1);
    __builtin_amdgcn_s_barrier();
    MFMA16(0, 1, bF1);

    // p3: quadrant (1,1) — fresh A-half1, reuse B1; stage t+2.A0
    LDA8(d, 1);
    if (t + 2 < NT) stageA(d, 0, k2);
    __builtin_amdgcn_s_barrier();
    MFMA16(1, 1, bF1);

    // p4: quadrant (1,0) — zero reads, reuse A1+B0; stage t+2.B0; counted wait
    if (t + 2 < NT) {
      stageB(d, 0, k2);
      asm volatile("s_waitcnt vmcnt(4)" ::: "memory");  // tile t+1 fully resident
    } else {
      asm volatile("s_waitcnt vmcnt(0)" ::: "memory");
    }
    __builtin_amdgcn_s_barrier();
    MFMA16(1, 0, bF0);
  }

  // ---- epilogue: C/D layout col = lane&15, row = quad*4 + r ----
#pragma unroll
  for (int i = 0; i < 8; ++i) {
    const int gmb = m0 + wr * 128 + (i >> 2) * 64 + (i & 3) * 16 + quad * 4;
#pragma unroll
    for (int j = 0; j < 4; ++j) {
      const int gn = n0 + wc * 64 + (j >> 1) * 32 + (j & 1) * 16 + lr;
      float bv = 0.0f;
      if constexpr (EPI != EPI_SCORES) {
        // gn>=1024 is block-uniform (256-wide n-tiles, 1024-aligned split)
        bv = (bias2 && gn >= 1024) ? bias2[gn - 1024] : (bias ? bias[gn] : 0.0f);
      }
#pragma unroll
      for (int r = 0; r < 4; ++r) {
        float v = acc[i][j][r];
        const size_t off = (size_t)z * (size_t)sC + (size_t)(gmb + r) * ldc + gn;
        if constexpr (EPI == EPI_BF16) {
          v += bv;
          if (RELU) v = v > 0.0f ? v : 0.0f;
          ((bf16_t*)Cv)[off] = f2bf(v);
        } else if constexpr (EPI == EPI_SCORES) {
          const int mk = mask[(size_t)z * (size_t)sMask + gn];
          ((float*)Cv)[off] = mk ? v * scale : -1e9f;
        } else {
          ((float*)Cv)[off] = v + bv + resid[(size_t)(gmb + r) * ldc + gn];
        }
      }
    }
  }
}

// ---------------------------------------------------------------------------
// LayerNorm over D=1024: one block / row, 256 threads x float4. Output bf16.
// ---------------------------------------------------------------------------
__global__ __launch_bounds__(256)
void ln_kernel(const float* __restrict__ x, const float* __restrict__ g,
               const float* __restrict__ b, bf16_t* __restrict__ out)
{
  const int row  = blockIdx.x;
  const int t    = threadIdx.x;
  const int wave = t >> 6, lane = t & 63;
  const float4 v = ((const float4*)(x + (size_t)row * DD))[t];

  float s = v.x + v.y + v.z + v.w;
#pragma unroll
  for (int o = 32; o > 0; o >>= 1) s += __shfl_down(s, o);
  __shared__ float red1[4], red2[4];
  if (lane == 0) red1[wave] = s;
  __syncthreads();
  const float mu = (red1[0] + red1[1] + red1[2] + red1[3]) * (1.0f / DD);

  const float d0 = v.x - mu, d1 = v.y - mu, d2 = v.z - mu, d3 = v.w - mu;
  float ss = d0 * d0 + d1 * d1 + d2 * d2 + d3 * d3;
#pragma unroll
  for (int o = 32; o > 0; o >>= 1) ss += __shfl_down(ss, o);
  if (lane == 0) red2[wave] = ss;
  __syncthreads();
  const float var = (red2[0] + red2[1] + red2[2] + red2[3]) * (1.0f / DD);
  const float rs  = rsqrtf(var + 1e-5f);

  const float4 gg = ((const float4*)g)[t];
  const float4 bb = ((const float4*)b)[t];
  short4v o;
  o.x = (short)f2bf(d0 * rs * gg.x + bb.x);
  o.y = (short)f2bf(d1 * rs * gg.y + bb.y);
  o.z = (short)f2bf(d2 * rs * gg.z + bb.z);
  o.w = (short)f2bf(d3 * rs * gg.w + bb.w);
  *(short4v*)(out + (size_t)row * DD + t * 4) = o;
}

// ---------------------------------------------------------------------------
// Row softmax over S=2048, dual output: f32 in-place + bf16 copy.
// ---------------------------------------------------------------------------
__global__ __launch_bounds__(256)
void softmax_kernel(float* __restrict__ w, bf16_t* __restrict__ wb)
{
  const size_t rowoff = (size_t)blockIdx.x * SS;
  float* p = w + rowoff;
  const int t = threadIdx.x;
  const int wave = t >> 6, lane = t & 63;
  float4 v0 = ((float4*)p)[t];
  float4 v1 = ((float4*)p)[t + 256];

  float m = fmaxf(fmaxf(fmaxf(v0.x, v0.y), fmaxf(v0.z, v0.w)),
                  fmaxf(fmaxf(v1.x, v1.y), fmaxf(v1.z, v1.w)));
#pragma unroll
  for (int o = 32; o > 0; o >>= 1) m = fmaxf(m, __shfl_down(m, o));
  __shared__ float red1[4], red2[4];
  if (lane == 0) red1[wave] = m;
  __syncthreads();
  m = fmaxf(fmaxf(red1[0], red1[1]), fmaxf(red1[2], red1[3]));

  v0.x = __expf(v0.x - m); v0.y = __expf(v0.y - m);
  v0.z = __expf(v0.z - m); v0.w = __expf(v0.w - m);
  v1.x = __expf(v1.x - m); v1.y = __expf(v1.y - m);
  v1.z = __expf(v1.z - m); v1.w = __expf(v1.w - m);

  float s = v0.x + v0.y + v0.z + v0.w + v1.x + v1.y + v1.z + v1.w;
#pragma unroll
  for (int o = 32; o > 0; o >>= 1) s += __shfl_down(s, o);
  if (lane == 0) red2[wave] = s;
  __syncthreads();
  const float inv = 1.0f / (red2[0] + red2[1] + red2[2] + red2[3]);

  v0.x *= inv; v0.y *= inv; v0.z *= inv; v0.w *= inv;
  v1.x *= inv; v1.y *= inv; v1.z *= inv; v1.w *= inv;
  ((float4*)p)[t] = v0;
  ((float4*)p)[t + 256] = v1;

  short4v o0 = { (short)f2bf(v0.x), (short)f2bf(v0.y), (short)f2bf(v0.z), (short)f2bf(v0.w) };
  short4v o1 = { (short)f2bf(v1.x), (short)f2bf(v1.y), (short)f2bf(v1.z), (short)f2bf(v1.w) };
  *(short4v*)(wb + rowoff + t * 4)         = o0;
  *(short4v*)(wb + rowoff + (t + 256) * 4) = o1;
}

// ---------------------------------------------------------------------------
// Tiled transpose (+convert) to bf16: in [R,C](ldin) -> out [C,R]. block (32,8).
// ---------------------------------------------------------------------------
template <typename ST>
__global__ __launch_bounds__(256)
void transpose_to_bf16(const ST* __restrict__ in, bf16_t* __restrict__ out,
                       int R, int C, int ldin, long long inB, long long outB)
{
  __shared__ float tile[32][33];
  const int tx = threadIdx.x, ty = threadIdx.y;
  const size_t zi = (size_t)blockIdx.z * (size_t)inB;
  const size_t zo = (size_t)blockIdx.z * (size_t)outB;
  const int c0 = blockIdx.x * 32, r0 = blockIdx.y * 32;
#pragma unroll
  for (int k = 0; k < 32; k += 8) {
    ST raw = in[zi + (size_t)(r0 + ty + k) * ldin + (c0 + tx)];
    float v;
    if constexpr (sizeof(ST) == 2) {
      v = __uint_as_float(((unsigned)(unsigned short)raw) << 16);
    } else {
      v = (float)raw;
    }
    tile[ty + k][tx] = v;
  }
  __syncthreads();
#pragma unroll
  for (int k = 0; k < 32; k += 8)
    out[zo + (size_t)(c0 + ty + k) * R + (r0 + tx)] = f2bf(tile[tx][ty + k]);
}

// ---------------------------------------------------------------------------
extern "C" void kernel_launch(void* const* d_in, const int* in_sizes, int n_in,
                              void* d_out, int out_size, void* d_ws, size_t ws_size,
                              hipStream_t stream)
{
  const float* x    = (const float*)d_in[0];
  const int*   mask = (const int*)d_in[1];
  const float* ln1g = (const float*)d_in[2];
  const float* ln1b = (const float*)d_in[3];
  const float* Wq   = (const float*)d_in[4];
  const float* bq   = (const float*)d_in[5];
  const float* Wk   = (const float*)d_in[6];
  const float* bk   = (const float*)d_in[7];
  const float* Wo   = (const float*)d_in[8];
  const float* bo   = (const float*)d_in[9];
  const float* ln2g = (const float*)d_in[10];
  const float* ln2b = (const float*)d_in[11];
  const float* W1   = (const float*)d_in[12];
  const float* b1   = (const float*)d_in[13];
  const float* W2   = (const float*)d_in[14];
  const float* b2   = (const float*)d_in[15];

  float* out  = (float*)d_out;                       // (B,S,D) f32, 64MB
  float* wout = out + (size_t)BB * SS * DD;          // (B,S,S) f32, 128MB

  // ---- workspace layout (~170 MB), plus d_out-region reuse ----
  char* ws = (char*)d_ws;
  size_t off = 0;
  auto alloc = [&](size_t bytes) {
    char* p = ws + off; off += (bytes + 255) & ~(size_t)255; return p;
  };
  bf16_t* WqkT = (bf16_t*)alloc((size_t)2 * DD * DD * 2);   // [2048,1024] = WqT ; WkT
  bf16_t* WoT  = (bf16_t*)alloc((size_t)DD * DD * 2);
  bf16_t* W1T  = (bf16_t*)alloc((size_t)DD * DD * 2);
  bf16_t* W2T  = (bf16_t*)alloc((size_t)DD * DD * 2);
  bf16_t* QKb  = (bf16_t*)alloc((size_t)BB * SS * 2 * DD * 2);  // [16384,2048] bf16, 64MB
  char*   Rwb  = alloc((size_t)64 * 1024 * 1024);               // wbf -> xn2+h
  bf16_t* aV   = (bf16_t*)alloc((size_t)BB * SS * DD * 2);      // 32MB

  bf16_t* wbf = (bf16_t*)Rwb;                      // (B,S,S) bf16, dies after w@V
  bf16_t* xn2 = (bf16_t*)Rwb;                      // (B*S,D) bf16 (after wbf dead)
  bf16_t* h   = (bf16_t*)(Rwb + (size_t)32 * 1024 * 1024);  // (B*S,D_FF) bf16

  // d_out reuse: xn lives in wout region (dead before scores written);
  // KT lives in out region (dead before x2 born); x2 lives in out region.
  bf16_t* xn = (bf16_t*)wout;                      // (B*S,D) bf16, dies step 3
  bf16_t* KT = (bf16_t*)out;                       // (B,D,S) bf16, steps 6-7
  float*  x2 = out;                                // (B*S,D) f32, from step 8

  const dim3 tb(256);
  const dim3 tg(512);
  const dim3 tt(32, 8);
  const long long SD   = (long long)SS * DD;       // 2M elems
  const long long S2   = (long long)SS * SS;       // 4M elems
  const long long QKs  = (long long)SS * 2 * DD;   // per-batch elems in QKb

  // 1. weights -> transposed bf16 [N][K]; Wq,Wk concatenated
  transpose_to_bf16<float><<<dim3(32, 32, 1), tt, 0, stream>>>(Wq, WqkT, DD, DD, DD, 0, 0);
  transpose_to_bf16<float><<<dim3(32, 32, 1), tt, 0, stream>>>(Wk, WqkT + (size_t)DD * DD, DD, DD, DD, 0, 0);
  transpose_to_bf16<float><<<dim3(32, 32, 1), tt, 0, stream>>>(Wo, WoT, DD, DD, DD, 0, 0);
  transpose_to_bf16<float><<<dim3(32, 32, 1), tt, 0, stream>>>(W1, W1T, DD, DD, DD, 0, 0);
  transpose_to_bf16<float><<<dim3(32, 32, 1), tt, 0, stream>>>(W2, W2T, DD, DD, DD, 0, 0);

  // 2. xn = LN1(x)
  ln_kernel<<<dim3(BB * SS), tb, 0, stream>>>(x, ln1g, ln1b, xn);

  // 3. QK = xn @ [Wq|Wk] + [bq|bk]   (bf16, [16384,2048])
  gemm256<EPI_BF16, false><<<dim3(512), tg, 0, stream>>>(
      xn, WqkT, QKb, bq, bk, nullptr, nullptr,
      /*Mt,Nt,Z,nc*/ 64, 8, 1, 8, /*K,lda,ldb,ldc*/ DD, DD, DD, 2 * DD,
      0, 0, 0, 0, 1.0f);

  // 4. scores = Q K^T / 32, masked -> wout (f32). Per-XCD chunk == one batch.
  gemm256<EPI_SCORES, false><<<dim3(512), tg, 0, stream>>>(
      QKb, QKb + DD, wout, nullptr, nullptr, nullptr, mask,
      8, 8, BB, 8, /*K,lda,ldb,ldc*/ DD, 2 * DD, 2 * DD, SS,
      QKs, QKs, S2, SS, 0.03125f);

  // 5. softmax rows -> wout (f32) + wbf (bf16)
  softmax_kernel<<<dim3(BB * SS), tb, 0, stream>>>(wout, wbf);

  // 6. V^T: transpose K (cols 1024..2047 of QKb) per batch -> KT [D,S]
  transpose_to_bf16<bf16_t><<<dim3(32, 64, BB), tt, 0, stream>>>(
      QKb + DD, KT, SS, DD, 2 * DD, QKs, SD);

  // 7. attnV = w @ V   (bf16)
  gemm256<EPI_BF16, false><<<dim3(256), tg, 0, stream>>>(
      wbf, KT, aV, nullptr, nullptr, nullptr, nullptr,
      8, 4, BB, 4, /*K,lda,ldb,ldc*/ SS, SS, SS, DD,
      S2, SD, SD, 0, 1.0f);

  // 8. x2 = x + attnV@Wo + bo  (f32, into out region)
  gemm256<EPI_RESID, false><<<dim3(256), tg, 0, stream>>>(
      aV, WoT, x2, bo, nullptr, x, nullptr,
      64, 4, 1, 4, DD, DD, DD, DD, 0, 0, 0, 0, 1.0f);

  // 9. xn2 = LN2(x2)
  ln_kernel<<<dim3(BB * SS), tb, 0, stream>>>(x2, ln2g, ln2b, xn2);

  // 10. h = relu(xn2@W1 + b1)  (bf16)
  gemm256<EPI_BF16, true><<<dim3(256), tg, 0, stream>>>(
      xn2, W1T, h, b1, nullptr, nullptr, nullptr,
      64, 4, 1, 4, DD, DD, DD, DD, 0, 0, 0, 0, 1.0f);

  // 11. out = x2 + h@W2 + b2  (f32, elementwise RMW of out region)
  gemm256<EPI_RESID, false><<<dim3(256), tg, 0, stream>>>(
      h, W2T, out, b2, nullptr, x2, nullptr,
      64, 4, 1, 4, DD, DD, DD, DD, 0, 0, 0, 0, 1.0f);
}

// Round 4
// 686.173 us; speedup vs baseline: 1.2946x; 1.0052x over previous
//
#include <hip/hip_runtime.h>
#include <cstdint>
#include <cstddef>

// Problem shape (fixed by reference): B=8, S=2048, D=1024, D_FF=1024
#define BB 8
#define SS 2048
#define DD 1024

typedef unsigned short bf16_t;                                  // raw bf16 bits
typedef __attribute__((ext_vector_type(8))) short bf16x8;       // MFMA A/B frag (4 VGPRs)
typedef __attribute__((ext_vector_type(4))) float f32x4;        // MFMA C/D frag
typedef __attribute__((ext_vector_type(4))) short short4v;

#define EPI_BF16   0   // C = bf16(acc + bias), optional ReLU  (LDS-bounce coalesced store)
#define EPI_SCORES 1   // C = mask ? acc*scale : -1e9  (f32)
#define EPI_RESID  2   // C = acc + bias + resid       (f32, same-element RMW safe)

__device__ __forceinline__ bf16_t f2bf(float f) {
  union { float f; unsigned u; } v; v.f = f;
  unsigned r = v.u + 0x7FFFu + ((v.u >> 16) & 1u);   // RNE
  return (bf16_t)(r >> 16);
}

// async global->LDS, 16B per lane. LDS dst must be wave-uniform base + lane*16.
__device__ __forceinline__ void async_copy16(const void* g, void* l) {
  auto gp = reinterpret_cast<unsigned int __attribute__((address_space(1)))*>(
      reinterpret_cast<uintptr_t>(g));
  auto lp = reinterpret_cast<unsigned int __attribute__((address_space(3)))*>(
      reinterpret_cast<uintptr_t>(l));
  __builtin_amdgcn_global_load_lds(gp, lp, 16, 0, 0);
}

// ---------------------------------------------------------------------------
// 256x256 NT GEMM: C[M,N] = A[M,K] * BT[N,K]^T, bf16 in, f32 acc.
// BK=64, 512 threads (8 waves, 2x4), per-wave 128x64 out, 16x16x32 MFMA.
// LDS 128 KiB: [2 dbuf][ A: 2 mh-halves 128x64 | B: 2 nh-halves 128x64 ].
// Swizzle: 16B-slot p holds logical slot p^(row&7)  (involution; applied on
// the global SOURCE address in staging and on the ds_read address — rule 21).
// Single barrier per phase; counted vmcnt(4); fragment-reuse order
// (0,0)->(0,1)->(1,1)->(1,0): 24 ds_read_b128/tile (data minimum).
// This core is at its staging-BW bound (~55-60% MfmaUtil) — do not re-tweak.
// ---------------------------------------------------------------------------
#define MM(i, j, Af, Bf) \
  acc[i][j] = __builtin_amdgcn_mfma_f32_16x16x32_bf16(Af, Bf, acc[i][j], 0, 0, 0)

#define LDA8(D, MH)                                                        \
  { const char* Ah_ = ldsc + (D) * 65536 + (MH) * 16384;                   \
    aF[0] = *(const bf16x8*)(Ah_ + aro +    0 + s0);                       \
    aF[1] = *(const bf16x8*)(Ah_ + aro + 2048 + s0);                       \
    aF[2] = *(const bf16x8*)(Ah_ + aro + 4096 + s0);                       \
    aF[3] = *(const bf16x8*)(Ah_ + aro + 6144 + s0);                       \
    aF[4] = *(const bf16x8*)(Ah_ + aro +    0 + s1);                       \
    aF[5] = *(const bf16x8*)(Ah_ + aro + 2048 + s1);                       \
    aF[6] = *(const bf16x8*)(Ah_ + aro + 4096 + s1);                       \
    aF[7] = *(const bf16x8*)(Ah_ + aro + 6144 + s1); }

#define LDB4(D, NH, BF)                                                    \
  { const char* Bh_ = ldsc + (D) * 65536 + 32768 + (NH) * 16384;           \
    BF[0] = *(const bf16x8*)(Bh_ + bro +    0 + s0);                       \
    BF[1] = *(const bf16x8*)(Bh_ + bro + 2048 + s0);                       \
    BF[2] = *(const bf16x8*)(Bh_ + bro +    0 + s1);                       \
    BF[3] = *(const bf16x8*)(Bh_ + bro + 2048 + s1); }

// prioritized 16-MFMA cluster (one C-quadrant); compiler inserts lgkm waits
#define MFMA16(MH, NH, BF)                                                 \
  __builtin_amdgcn_s_setprio(1);                                           \
  MM((MH)*4+0,(NH)*2+0,aF[0],BF[0]); MM((MH)*4+1,(NH)*2+0,aF[1],BF[0]);    \
  MM((MH)*4+2,(NH)*2+0,aF[2],BF[0]); MM((MH)*4+3,(NH)*2+0,aF[3],BF[0]);    \
  MM((MH)*4+0,(NH)*2+1,aF[0],BF[1]); MM((MH)*4+1,(NH)*2+1,aF[1],BF[1]);    \
  MM((MH)*4+2,(NH)*2+1,aF[2],BF[1]); MM((MH)*4+3,(NH)*2+1,aF[3],BF[1]);    \
  MM((MH)*4+0,(NH)*2+0,aF[4],BF[2]); MM((MH)*4+1,(NH)*2+0,aF[5],BF[2]);    \
  MM((MH)*4+2,(NH)*2+0,aF[6],BF[2]); MM((MH)*4+3,(NH)*2+0,aF[7],BF[2]);    \
  MM((MH)*4+0,(NH)*2+1,aF[4],BF[3]); MM((MH)*4+1,(NH)*2+1,aF[5],BF[3]);    \
  MM((MH)*4+2,(NH)*2+1,aF[6],BF[3]); MM((MH)*4+3,(NH)*2+1,aF[7],BF[3]);    \
  __builtin_amdgcn_s_setprio(0);

template <int EPI, bool RELU>
__global__ __launch_bounds__(512, 2)
void gemm256(const bf16_t* __restrict__ A, const bf16_t* __restrict__ BT,
             void* __restrict__ Cv,
             const float* __restrict__ bias,   // [<=ldc] or null
             const float* __restrict__ bias2,  // second-half bias (fused QK) or null
             const float* __restrict__ resid,  // [M,ldc] f32 (EPI_RESID)
             const int* __restrict__ mask,     // per-batch mask (EPI_SCORES)
             int Mt, int Nt, int Z, int nchunk,
             int K, int lda, int ldb, int ldc,
             long long sA, long long sB, long long sC, long long sMask,
             float scale)
{
  __shared__ __align__(16) bf16_t lds_[65536];   // 128 KiB
  char* ldsc = (char*)lds_;

  // ---- XCD swizzle: contiguous idx chunk per XCD ----
  const int b = blockIdx.x;
  const int Cchunk = (Z * Mt * Nt) >> 3;           // grid divisible by 8
  int idx = (b & 7) * Cchunk + (b >> 3);
  const int per_z = Mt * Nt;
  const int z = idx / per_z;  idx -= z * per_z;
  const int per_nc = Mt * nchunk;
  const int nc = idx / per_nc; idx -= nc * per_nc;
  const int mt = idx / nchunk;
  const int nin = idx - mt * nchunk;
  const int m0 = mt * 256;
  const int n0 = (nc * nchunk + nin) * 256;

  const int tid  = threadIdx.x;
  const int wave = tid >> 6;
  const int lane = tid & 63;
  const int wr   = wave >> 2, wc = wave & 3;       // 2 x 4 wave grid
  const int lr   = lane & 15, quad = lane >> 4;

  const bf16_t* Ab = A  + (size_t)z * (size_t)sA;
  const bf16_t* Bb = BT + (size_t)z * (size_t)sB;

  f32x4 acc[8][4];
#pragma unroll
  for (int i = 0; i < 8; ++i)
#pragma unroll
    for (int j = 0; j < 4; ++j)
#pragma unroll
      for (int r = 0; r < 4; ++r) acc[i][j][r] = 0.0f;

  // ---- staging geometry, hoisted: per-thread base pointers computed once.
  // Physical 16B slot p within a row holds logical k-chunk p^(row&7).
  const bf16_t* gA[2]; const bf16_t* gB[2]; char* lA[2]; char* lB[2];
#pragma unroll
  for (int u = 0; u < 2; ++u) {
    const int c = tid + u * 512;
    const int rl = c >> 3;
    const int csw = (((c & 7) ^ (rl & 7)) << 3);                 // swizzled k-elems
    const int rowA = ((rl & 64) << 1) + (rl & 63);               // rows 0..63,128..191
    const int rowB = ((rl & 96) << 1) + (rl & 31);               // rows 0..31,64..95,...
    gA[u] = Ab + (size_t)(m0 + rowA) * lda + csw;
    gB[u] = Bb + (size_t)(n0 + rowB) * ldb + csw;
    lA[u] = ldsc + c * 16;
    lB[u] = ldsc + 32768 + c * 16;
  }
  const int ldA64 = lda << 6, ldB64 = ldb << 5;    // A: +64 rows; B: +32 rows per nh

  auto stageA = [&](int d, int mh, int kt) {
    const int go = mh * ldA64 + kt;
    const int lo = d * 65536 + mh * 16384;
#pragma unroll
    for (int u = 0; u < 2; ++u) async_copy16(gA[u] + go, lA[u] + lo);
  };
  auto stageB = [&](int d, int nh, int kt) {
    const int go = nh * ldB64 + kt;
    const int lo = d * 65536 + nh * 16384;
#pragma unroll
    for (int u = 0; u < 2; ++u) async_copy16(gB[u] + go, lB[u] + lo);
  };

  // ds_read addressing: logical slot s = ks*4+quad; physical = s^(lr&7)
  const int s0  = ((quad ^ (lr & 7)) << 4);        // ks=0 byte offset in row
  const int s1  = s0 ^ 64;                          // ks=1
  const int aro = (wr * 64 + lr) << 7;              // A local-row byte base
  const int bro = (wc * 32 + lr) << 7;              // B local-row byte base

  bf16x8 aF[8];          // current A-half fragments (4 rows x 2 ks)
  bf16x8 bF0[4], bF1[4]; // B-half fragment sets (2 cols x 2 ks each)

  const int NT = K >> 6;

  // ---- prologue: tile0 (4 halves) + tile1 (A-mh0, B-nh0) ----
  stageA(0, 0, 0); stageA(0, 1, 0); stageB(0, 0, 0); stageB(0, 1, 0);
  if (NT > 1) {
    stageA(1, 0, 64); stageB(1, 0, 64);
    asm volatile("s_waitcnt vmcnt(4)" ::: "memory");   // tile0 resident
  } else {
    asm volatile("s_waitcnt vmcnt(0)" ::: "memory");
  }
  __builtin_amdgcn_s_barrier();

#pragma unroll 2
  for (int t = 0; t < NT; ++t) {
    const int d  = t & 1;
    const int k1 = (t + 1) << 6;
    const int k2 = (t + 2) << 6;

    // p1: quadrant (0,0) — fresh A-half0 + B-half0; stage t+1.A1
    LDA8(d, 0); LDB4(d, 0, bF0);
    if (t + 1 < NT) stageA(d ^ 1, 1, k1);
    __builtin_amdgcn_s_barrier();
    MFMA16(0, 0, bF0);

    // p2: quadrant (0,1) — reuse A0, fresh B-half1; stage t+1.B1
    LDB4(d, 1, bF1);
    if (t + 1 < NT) stageB(d ^ 1, 1, k1);
    __builtin_amdgcn_s_barrier();
    MFMA16(0, 1, bF1);

    // p3: quadrant (1,1) — fresh A-half1, reuse B1; stage t+2.A0
    LDA8(d, 1);
    if (t + 2 < NT) stageA(d, 0, k2);
    __builtin_amdgcn_s_barrier();
    MFMA16(1, 1, bF1);

    // p4: quadrant (1,0) — zero reads, reuse A1+B0; stage t+2.B0; counted wait
    if (t + 2 < NT) {
      stageB(d, 0, k2);
      asm volatile("s_waitcnt vmcnt(4)" ::: "memory");  // tile t+1 fully resident
    } else {
      asm volatile("s_waitcnt vmcnt(0)" ::: "memory");
    }
    __builtin_amdgcn_s_barrier();
    MFMA16(1, 0, bF0);
  }

  // ---- epilogue ----
  // C/D layout: col = lane&15, row = quad*4 + r  [verified m89/m91]
  if constexpr (EPI == EPI_BF16) {
    // LDS-bounce coalesced store. Per-wave private 16KB region ([128 m][64 n]
    // bf16, 16B-chunk XOR-swizzle by m&7). Safe without a barrier: all waves'
    // main-loop ds_reads complete before the final loop barrier.
    char* Wb = ldsc + wave * 16384;
#pragma unroll
    for (int i = 0; i < 8; ++i) {
      const int mb = (i >> 2) * 64 + (i & 3) * 16 + quad * 4;     // + r
#pragma unroll
      for (int j = 0; j < 4; ++j) {
        const int nl = (j >> 1) * 32 + (j & 1) * 16 + lr;         // 0..63
        const int gn = n0 + wc * 64 + nl;
        const float bv = (bias2 && gn >= 1024) ? bias2[gn - 1024]
                       : (bias ? bias[gn] : 0.0f);
#pragma unroll
        for (int r = 0; r < 4; ++r) {
          float v = acc[i][j][r] + bv;
          if (RELU) v = fmaxf(v, 0.0f);
          const int m = mb + r;
          const int nb = nl * 2;
          const int phys = (m << 7) + (((nb & ~15) ^ ((m & 7) << 4)) | (nb & 15));
          *(bf16_t*)(Wb + phys) = f2bf(v);
        }
      }
    }
    asm volatile("s_waitcnt lgkmcnt(0)" ::: "memory");  // writes visible to own reads
    bf16_t* Cb = (bf16_t*)Cv + (size_t)z * (size_t)sC
               + (size_t)(m0 + wr * 128) * ldc + (n0 + wc * 64);
#pragma unroll
    for (int p = 0; p < 16; ++p) {
      const int m = p * 8 + (lane >> 3);
      const int c = lane & 7;
      const bf16x8 vv = *(const bf16x8*)(Wb + (m << 7) + (((c ^ (m & 7)) << 4)));
      *(bf16x8*)(Cb + (size_t)m * ldc + c * 8) = vv;
    }
  } else {
#pragma unroll
    for (int i = 0; i < 8; ++i) {
      const int gmb = m0 + wr * 128 + (i >> 2) * 64 + (i & 3) * 16 + quad * 4;
#pragma unroll
      for (int j = 0; j < 4; ++j) {
        const int gn = n0 + wc * 64 + (j >> 1) * 32 + (j & 1) * 16 + lr;
        float bv = 0.0f;
        if constexpr (EPI == EPI_RESID) { bv = bias ? bias[gn] : 0.0f; }
#pragma unroll
        for (int r = 0; r < 4; ++r) {
          float v = acc[i][j][r];
          const size_t off = (size_t)z * (size_t)sC + (size_t)(gmb + r) * ldc + gn;
          if constexpr (EPI == EPI_SCORES) {
            const int mk = mask[(size_t)z * (size_t)sMask + gn];
            ((float*)Cv)[off] = mk ? v * scale : -1e9f;
          } else {
            ((float*)Cv)[off] = v + bv + resid[(size_t)(gmb + r) * ldc + gn];
          }
        }
      }
    }
  }
}

// ---------------------------------------------------------------------------
// Shared device bodies: LayerNorm row, softmax row, 32x32 tile transpose.
// ---------------------------------------------------------------------------
__device__ __forceinline__ void ln_body(const float* __restrict__ x,
                                        const float* __restrict__ g,
                                        const float* __restrict__ b,
                                        bf16_t* __restrict__ out,
                                        int row, int t, float* red)
{
  const int wave = t >> 6, lane = t & 63;
  const float4 v = ((const float4*)(x + (size_t)row * DD))[t];

  float s = v.x + v.y + v.z + v.w;
#pragma unroll
  for (int o = 32; o > 0; o >>= 1) s += __shfl_down(s, o);
  if (lane == 0) red[wave] = s;
  __syncthreads();
  const float mu = (red[0] + red[1] + red[2] + red[3]) * (1.0f / DD);

  const float d0 = v.x - mu, d1 = v.y - mu, d2 = v.z - mu, d3 = v.w - mu;
  float ss = d0 * d0 + d1 * d1 + d2 * d2 + d3 * d3;
#pragma unroll
  for (int o = 32; o > 0; o >>= 1) ss += __shfl_down(ss, o);
  if (lane == 0) red[4 + wave] = ss;
  __syncthreads();
  const float var = (red[4] + red[5] + red[6] + red[7]) * (1.0f / DD);
  const float rs  = rsqrtf(var + 1e-5f);

  const float4 gg = ((const float4*)g)[t];
  const float4 bb = ((const float4*)b)[t];
  short4v o;
  o.x = (short)f2bf(d0 * rs * gg.x + bb.x);
  o.y = (short)f2bf(d1 * rs * gg.y + bb.y);
  o.z = (short)f2bf(d2 * rs * gg.z + bb.z);
  o.w = (short)f2bf(d3 * rs * gg.w + bb.w);
  *(short4v*)(out + (size_t)row * DD + t * 4) = o;
}

__device__ __forceinline__ void softmax_body(float* __restrict__ w,
                                             bf16_t* __restrict__ wb,
                                             int row, int t, float* red)
{
  const size_t rowoff = (size_t)row * SS;
  float* p = w + rowoff;
  const int wave = t >> 6, lane = t & 63;
  float4 v0 = ((float4*)p)[t];
  float4 v1 = ((float4*)p)[t + 256];

  float m = fmaxf(fmaxf(fmaxf(v0.x, v0.y), fmaxf(v0.z, v0.w)),
                  fmaxf(fmaxf(v1.x, v1.y), fmaxf(v1.z, v1.w)));
#pragma unroll
  for (int o = 32; o > 0; o >>= 1) m = fmaxf(m, __shfl_down(m, o));
  if (lane == 0) red[wave] = m;
  __syncthreads();
  m = fmaxf(fmaxf(red[0], red[1]), fmaxf(red[2], red[3]));

  v0.x = __expf(v0.x - m); v0.y = __expf(v0.y - m);
  v0.z = __expf(v0.z - m); v0.w = __expf(v0.w - m);
  v1.x = __expf(v1.x - m); v1.y = __expf(v1.y - m);
  v1.z = __expf(v1.z - m); v1.w = __expf(v1.w - m);

  float s = v0.x + v0.y + v0.z + v0.w + v1.x + v1.y + v1.z + v1.w;
#pragma unroll
  for (int o = 32; o > 0; o >>= 1) s += __shfl_down(s, o);
  if (lane == 0) red[4 + wave] = s;
  __syncthreads();
  const float inv = 1.0f / (red[4] + red[5] + red[6] + red[7]);

  v0.x *= inv; v0.y *= inv; v0.z *= inv; v0.w *= inv;
  v1.x *= inv; v1.y *= inv; v1.z *= inv; v1.w *= inv;
  ((float4*)p)[t] = v0;
  ((float4*)p)[t + 256] = v1;

  short4v o0 = { (short)f2bf(v0.x), (short)f2bf(v0.y), (short)f2bf(v0.z), (short)f2bf(v0.w) };
  short4v o1 = { (short)f2bf(v1.x), (short)f2bf(v1.y), (short)f2bf(v1.z), (short)f2bf(v1.w) };
  *(short4v*)(wb + rowoff + t * 4)         = o0;
  *(short4v*)(wb + rowoff + (t + 256) * 4) = o1;
}

template <typename ST>
__device__ __forceinline__ void transpose_body(const ST* __restrict__ in,
                                               bf16_t* __restrict__ out,
                                               int R, int ldin,
                                               long long inB, long long outB,
                                               int xb, int yb, int zb,
                                               int tx, int ty, float* tile)
{
  const size_t zi = (size_t)zb * (size_t)inB;
  const size_t zo = (size_t)zb * (size_t)outB;
  const int c0 = xb * 32, r0 = yb * 32;
#pragma unroll
  for (int k = 0; k < 32; k += 8) {
    ST raw = in[zi + (size_t)(r0 + ty + k) * ldin + (c0 + tx)];
    float v;
    if constexpr (sizeof(ST) == 2) {
      v = __uint_as_float(((unsigned)(unsigned short)raw) << 16);
    } else {
      v = (float)raw;
    }
    tile[(ty + k) * 33 + tx] = v;
  }
  __syncthreads();
#pragma unroll
  for (int k = 0; k < 32; k += 8)
    out[zo + (size_t)(c0 + ty + k) * R + (r0 + tx)] = f2bf(tile[tx * 33 + ty + k]);
}

// ---------------------------------------------------------------------------
// prep: 5 weight transposes (blocks 0..5119) + LN1 rows (blocks 5120..21503)
// ---------------------------------------------------------------------------
__global__ __launch_bounds__(256)
void prep_kernel(const float* __restrict__ Wq, const float* __restrict__ Wk,
                 const float* __restrict__ Wo, const float* __restrict__ W1,
                 const float* __restrict__ W2,
                 bf16_t* __restrict__ WqkT, bf16_t* __restrict__ WoT,
                 bf16_t* __restrict__ W1T, bf16_t* __restrict__ W2T,
                 const float* __restrict__ x, const float* __restrict__ g,
                 const float* __restrict__ b, bf16_t* __restrict__ xn)
{
  __shared__ float smem[32 * 33];
  const int bid = blockIdx.x;
  const int tid = threadIdx.x;
  if (bid < 5120) {
    const int wi = bid >> 10;
    const int rem = bid & 1023;
    const float* src = wi == 0 ? Wq : wi == 1 ? Wk : wi == 2 ? Wo : wi == 3 ? W1 : W2;
    bf16_t* dst = wi == 0 ? WqkT : wi == 1 ? (WqkT + (size_t)DD * DD)
                 : wi == 2 ? WoT : wi == 3 ? W1T : W2T;
    transpose_body<float>(src, dst, DD, DD, 0, 0,
                          rem & 31, rem >> 5, 0, tid & 31, tid >> 5, smem);
  } else {
    ln_body(x, g, b, xn, bid - 5120, tid, smem);
  }
}

// ---------------------------------------------------------------------------
// softkt: softmax rows (blocks 0..16383) + K->KT transpose (blocks 16384..32767)
// ---------------------------------------------------------------------------
__global__ __launch_bounds__(256)
void softkt_kernel(float* __restrict__ w, bf16_t* __restrict__ wb,
                   const bf16_t* __restrict__ qkb_k, bf16_t* __restrict__ KT)
{
  __shared__ float smem[32 * 33];
  const int bid = blockIdx.x;
  const int tid = threadIdx.x;
  if (bid < BB * SS) {
    softmax_body(w, wb, bid, tid, smem);
  } else {
    const int t2 = bid - BB * SS;          // 0..16383 = 32 x 64 x 8
    const int zb = t2 >> 11, rem = t2 & 2047;
    transpose_body<bf16_t>(qkb_k, KT, SS, 2 * DD,
                           (long long)SS * 2 * DD, (long long)SS * DD,
                           rem & 31, rem >> 5, zb, tid & 31, tid >> 5, smem);
  }
}

// ---------------------------------------------------------------------------
// standalone LN (for LN2)
// ---------------------------------------------------------------------------
__global__ __launch_bounds__(256)
void ln_kernel(const float* __restrict__ x, const float* __restrict__ g,
               const float* __restrict__ b, bf16_t* __restrict__ out)
{
  __shared__ float red[8];
  ln_body(x, g, b, out, blockIdx.x, threadIdx.x, red);
}

// ---------------------------------------------------------------------------
extern "C" void kernel_launch(void* const* d_in, const int* in_sizes, int n_in,
                              void* d_out, int out_size, void* d_ws, size_t ws_size,
                              hipStream_t stream)
{
  const float* x    = (const float*)d_in[0];
  const int*   mask = (const int*)d_in[1];
  const float* ln1g = (const float*)d_in[2];
  const float* ln1b = (const float*)d_in[3];
  const float* Wq   = (const float*)d_in[4];
  const float* bq   = (const float*)d_in[5];
  const float* Wk   = (const float*)d_in[6];
  const float* bk   = (const float*)d_in[7];
  const float* Wo   = (const float*)d_in[8];
  const float* bo   = (const float*)d_in[9];
  const float* ln2g = (const float*)d_in[10];
  const float* ln2b = (const float*)d_in[11];
  const float* W1   = (const float*)d_in[12];
  const float* b1   = (const float*)d_in[13];
  const float* W2   = (const float*)d_in[14];
  const float* b2   = (const float*)d_in[15];

  float* out  = (float*)d_out;                       // (B,S,D) f32, 64MB
  float* wout = out + (size_t)BB * SS * DD;          // (B,S,S) f32, 128MB

  // ---- workspace layout (~170 MB), plus d_out-region reuse ----
  char* ws = (char*)d_ws;
  size_t off = 0;
  auto alloc = [&](size_t bytes) {
    char* p = ws + off; off += (bytes + 255) & ~(size_t)255; return p;
  };
  bf16_t* WqkT = (bf16_t*)alloc((size_t)2 * DD * DD * 2);   // [2048,1024] = WqT ; WkT
  bf16_t* WoT  = (bf16_t*)alloc((size_t)DD * DD * 2);
  bf16_t* W1T  = (bf16_t*)alloc((size_t)DD * DD * 2);
  bf16_t* W2T  = (bf16_t*)alloc((size_t)DD * DD * 2);
  bf16_t* QKb  = (bf16_t*)alloc((size_t)BB * SS * 2 * DD * 2);  // [16384,2048] bf16, 64MB
  char*   Rwb  = alloc((size_t)64 * 1024 * 1024);               // wbf -> xn2+h
  bf16_t* aV   = (bf16_t*)alloc((size_t)BB * SS * DD * 2);      // 32MB

  bf16_t* wbf = (bf16_t*)Rwb;                      // (B,S,S) bf16, dies after w@V
  bf16_t* xn2 = (bf16_t*)Rwb;                      // (B*S,D) bf16 (after wbf dead)
  bf16_t* h   = (bf16_t*)(Rwb + (size_t)32 * 1024 * 1024);  // (B*S,D_FF) bf16

  // d_out reuse: xn lives in wout region (dead before scores written);
  // KT lives in out region (dead before x2 born); x2 lives in out region.
  bf16_t* xn = (bf16_t*)wout;                      // (B*S,D) bf16, dies step 3
  bf16_t* KT = (bf16_t*)out;                       // (B,D,S) bf16, steps 4-5
  float*  x2 = out;                                // (B*S,D) f32, from step 6

  const dim3 tb(256);
  const dim3 tg(512);
  const long long SD   = (long long)SS * DD;       // 2M elems
  const long long S2   = (long long)SS * SS;       // 4M elems
  const long long QKs  = (long long)SS * 2 * DD;   // per-batch elems in QKb

  // 1. prep: weights -> transposed bf16 [N][K] (Wq,Wk concatenated) + LN1
  prep_kernel<<<dim3(5120 + BB * SS), tb, 0, stream>>>(
      Wq, Wk, Wo, W1, W2, WqkT, WoT, W1T, W2T, x, ln1g, ln1b, xn);

  // 2. QK = xn @ [Wq|Wk] + [bq|bk]   (bf16, [16384,2048])
  gemm256<EPI_BF16, false><<<dim3(512), tg, 0, stream>>>(
      xn, WqkT, QKb, bq, bk, nullptr, nullptr,
      /*Mt,Nt,Z,nc*/ 64, 8, 1, 8, /*K,lda,ldb,ldc*/ DD, DD, DD, 2 * DD,
      0, 0, 0, 0, 1.0f);

  // 3. scores = Q K^T / 32, masked -> wout (f32). Per-XCD chunk == one batch.
  gemm256<EPI_SCORES, false><<<dim3(512), tg, 0, stream>>>(
      QKb, QKb + DD, wout, nullptr, nullptr, nullptr, mask,
      8, 8, BB, 8, /*K,lda,ldb,ldc*/ DD, 2 * DD, 2 * DD, SS,
      QKs, QKs, S2, SS, 0.03125f);

  // 4. softmax rows -> wout (f32) + wbf (bf16)  ||  V^T transpose -> KT [B,D,S]
  softkt_kernel<<<dim3(2 * BB * SS), tb, 0, stream>>>(wout, wbf, QKb + DD, KT);

  // 5. attnV = w @ V   (bf16)
  gemm256<EPI_BF16, false><<<dim3(256), tg, 0, stream>>>(
      wbf, KT, aV, nullptr, nullptr, nullptr, nullptr,
      8, 4, BB, 4, /*K,lda,ldb,ldc*/ SS, SS, SS, DD,
      S2, SD, SD, 0, 1.0f);

  // 6. x2 = x + attnV@Wo + bo  (f32, into out region)
  gemm256<EPI_RESID, false><<<dim3(256), tg, 0, stream>>>(
      aV, WoT, x2, bo, nullptr, x, nullptr,
      64, 4, 1, 4, DD, DD, DD, DD, 0, 0, 0, 0, 1.0f);

  // 7. xn2 = LN2(x2)
  ln_kernel<<<dim3(BB * SS), tb, 0, stream>>>(x2, ln2g, ln2b, xn2);

  // 8. h = relu(xn2@W1 + b1)  (bf16)
  gemm256<EPI_BF16, true><<<dim3(256), tg, 0, stream>>>(
      xn2, W1T, h, b1, nullptr, nullptr, nullptr,
      64, 4, 1, 4, DD, DD, DD, DD, 0, 0, 0, 0, 1.0f);

  // 9. out = x2 + h@W2 + b2  (f32, elementwise RMW of out region)
  gemm256<EPI_RESID, false><<<dim3(256), tg, 0, stream>>>(
      h, W2T, out, b2, nullptr, x2, nullptr,
      64, 4, 1, 4, DD, DD, DD, DD, 0, 0, 0, 0, 1.0f);
}

// Round 5
// 681.786 us; speedup vs baseline: 1.3030x; 1.0064x over previous
//
#include <hip/hip_runtime.h>
#include <cstdint>
#include <cstddef>

// Problem shape (fixed by reference): B=8, S=2048, D=1024, D_FF=1024
#define BB 8
#define SS 2048
#define DD 1024

typedef unsigned short bf16_t;                                  // raw bf16 bits
typedef __attribute__((ext_vector_type(8))) short bf16x8;       // MFMA A/B frag (4 VGPRs)
typedef __attribute__((ext_vector_type(4))) float f32x4;        // MFMA C/D frag
typedef __attribute__((ext_vector_type(4))) short short4v;

#define EPI_BF16   0   // C = bf16(acc + bias), optional ReLU  (bf16 LDS-bounce store)
#define EPI_SCORES 1   // C = mask ? acc*scale : -1e9  (f32, LDS-bounce coalesced)
#define EPI_RESID  2   // C = acc + bias + resid       (f32, LDS-bounce coalesced RMW)

__device__ __forceinline__ bf16_t f2bf(float f) {
  union { float f; unsigned u; } v; v.f = f;
  unsigned r = v.u + 0x7FFFu + ((v.u >> 16) & 1u);   // RNE
  return (bf16_t)(r >> 16);
}

// async global->LDS, 16B per lane. LDS dst must be wave-uniform base + lane*16.
__device__ __forceinline__ void async_copy16(const void* g, void* l) {
  auto gp = reinterpret_cast<unsigned int __attribute__((address_space(1)))*>(
      reinterpret_cast<uintptr_t>(g));
  auto lp = reinterpret_cast<unsigned int __attribute__((address_space(3)))*>(
      reinterpret_cast<uintptr_t>(l));
  __builtin_amdgcn_global_load_lds(gp, lp, 16, 0, 0);
}

// ---------------------------------------------------------------------------
// GEMM parameter block (by-value kernel arg)
// ---------------------------------------------------------------------------
struct GemmP {
  const bf16_t* __restrict__ A;
  const bf16_t* __restrict__ BT;
  void*         __restrict__ C;
  const float*  __restrict__ bias;   // [<=ldc] or null
  const float*  __restrict__ bias2;  // second-half bias (fused QK) or null
  const float*  __restrict__ resid;  // [Z,M,ldc] f32 (EPI_RESID)
  const int*    __restrict__ mask;   // per-batch mask (EPI_SCORES)
  int Mt, Nt, Z, nchunk;
  int K, lda, ldb, ldc;
  long long sA, sB, sC, sMask;
  float scale;
};

// ---------------------------------------------------------------------------
// 256x256 NT GEMM core: C[M,N] = A[M,K] * BT[N,K]^T, bf16 in, f32 acc.
// BK=64, 512 threads (8 waves, 2x4), per-wave 128x64 out, 16x16x32 MFMA.
// LDS 128 KiB: [2 dbuf][ A: 2 mh-halves 128x64 | B: 2 nh-halves 128x64 ].
// Swizzle: 16B-slot p holds logical slot p^(row&7) (both-sides, rule 21).
// Single barrier per phase; counted vmcnt(4); fragment-reuse order
// (0,0)->(0,1)->(1,1)->(1,0): 24 ds_read_b128/tile (data minimum).
// Core main loop is at its staging/LDS bound — byte-identical to r3/r4.
// ---------------------------------------------------------------------------
#define MM(i, j, Af, Bf) \
  acc[i][j] = __builtin_amdgcn_mfma_f32_16x16x32_bf16(Af, Bf, acc[i][j], 0, 0, 0)

#define LDA8(D, MH)                                                        \
  { const char* Ah_ = ldsc + (D) * 65536 + (MH) * 16384;                   \
    aF[0] = *(const bf16x8*)(Ah_ + aro +    0 + s0);                       \
    aF[1] = *(const bf16x8*)(Ah_ + aro + 2048 + s0);                       \
    aF[2] = *(const bf16x8*)(Ah_ + aro + 4096 + s0);                       \
    aF[3] = *(const bf16x8*)(Ah_ + aro + 6144 + s0);                       \
    aF[4] = *(const bf16x8*)(Ah_ + aro +    0 + s1);                       \
    aF[5] = *(const bf16x8*)(Ah_ + aro + 2048 + s1);                       \
    aF[6] = *(const bf16x8*)(Ah_ + aro + 4096 + s1);                       \
    aF[7] = *(const bf16x8*)(Ah_ + aro + 6144 + s1); }

#define LDB4(D, NH, BF)                                                    \
  { const char* Bh_ = ldsc + (D) * 65536 + 32768 + (NH) * 16384;           \
    BF[0] = *(const bf16x8*)(Bh_ + bro +    0 + s0);                       \
    BF[1] = *(const bf16x8*)(Bh_ + bro + 2048 + s0);                       \
    BF[2] = *(const bf16x8*)(Bh_ + bro +    0 + s1);                       \
    BF[3] = *(const bf16x8*)(Bh_ + bro + 2048 + s1); }

#define MFMA16(MH, NH, BF)                                                 \
  __builtin_amdgcn_s_setprio(1);                                           \
  MM((MH)*4+0,(NH)*2+0,aF[0],BF[0]); MM((MH)*4+1,(NH)*2+0,aF[1],BF[0]);    \
  MM((MH)*4+2,(NH)*2+0,aF[2],BF[0]); MM((MH)*4+3,(NH)*2+0,aF[3],BF[0]);    \
  MM((MH)*4+0,(NH)*2+1,aF[0],BF[1]); MM((MH)*4+1,(NH)*2+1,aF[1],BF[1]);    \
  MM((MH)*4+2,(NH)*2+1,aF[2],BF[1]); MM((MH)*4+3,(NH)*2+1,aF[3],BF[1]);    \
  MM((MH)*4+0,(NH)*2+0,aF[4],BF[2]); MM((MH)*4+1,(NH)*2+0,aF[5],BF[2]);    \
  MM((MH)*4+2,(NH)*2+0,aF[6],BF[2]); MM((MH)*4+3,(NH)*2+0,aF[7],BF[2]);    \
  MM((MH)*4+0,(NH)*2+1,aF[4],BF[3]); MM((MH)*4+1,(NH)*2+1,aF[5],BF[3]);    \
  MM((MH)*4+2,(NH)*2+1,aF[6],BF[3]); MM((MH)*4+3,(NH)*2+1,aF[7],BF[3]);    \
  __builtin_amdgcn_s_setprio(0);

template <int EPI, bool RELU>
__device__ __forceinline__ void gemm_core(const GemmP p, int b, char* ldsc)
{
  // ---- XCD swizzle: contiguous idx chunk per XCD ----
  const int Cchunk = (p.Z * p.Mt * p.Nt) >> 3;     // grid divisible by 8
  int idx = (b & 7) * Cchunk + (b >> 3);
  const int per_z = p.Mt * p.Nt;
  const int z = idx / per_z;  idx -= z * per_z;
  const int per_nc = p.Mt * p.nchunk;
  const int nc = idx / per_nc; idx -= nc * per_nc;
  const int mt = idx / p.nchunk;
  const int nin = idx - mt * p.nchunk;
  const int m0 = mt * 256;
  const int n0 = (nc * p.nchunk + nin) * 256;

  const int tid  = threadIdx.x;
  const int wave = tid >> 6;
  const int lane = tid & 63;
  const int wr   = wave >> 2, wc = wave & 3;       // 2 x 4 wave grid
  const int lr   = lane & 15, quad = lane >> 4;

  const bf16_t* Ab = p.A  + (size_t)z * (size_t)p.sA;
  const bf16_t* Bb = p.BT + (size_t)z * (size_t)p.sB;

  f32x4 acc[8][4];
#pragma unroll
  for (int i = 0; i < 8; ++i)
#pragma unroll
    for (int j = 0; j < 4; ++j)
#pragma unroll
      for (int r = 0; r < 4; ++r) acc[i][j][r] = 0.0f;

  // staging geometry, hoisted. Slot p holds logical k-chunk p^(row&7).
  const bf16_t* gA[2]; const bf16_t* gB[2]; char* lA[2]; char* lB[2];
#pragma unroll
  for (int u = 0; u < 2; ++u) {
    const int c = tid + u * 512;
    const int rl = c >> 3;
    const int csw = (((c & 7) ^ (rl & 7)) << 3);                 // swizzled k-elems
    const int rowA = ((rl & 64) << 1) + (rl & 63);               // rows 0..63,128..191
    const int rowB = ((rl & 96) << 1) + (rl & 31);
    gA[u] = Ab + (size_t)(m0 + rowA) * p.lda + csw;
    gB[u] = Bb + (size_t)(n0 + rowB) * p.ldb + csw;
    lA[u] = ldsc + c * 16;
    lB[u] = ldsc + 32768 + c * 16;
  }
  const int ldA64 = p.lda << 6, ldB64 = p.ldb << 5;

  auto stageA = [&](int d, int mh, int kt) {
    const int go = mh * ldA64 + kt;
    const int lo = d * 65536 + mh * 16384;
#pragma unroll
    for (int u = 0; u < 2; ++u) async_copy16(gA[u] + go, lA[u] + lo);
  };
  auto stageB = [&](int d, int nh, int kt) {
    const int go = nh * ldB64 + kt;
    const int lo = d * 65536 + nh * 16384;
#pragma unroll
    for (int u = 0; u < 2; ++u) async_copy16(gB[u] + go, lB[u] + lo);
  };

  // ds_read addressing: logical slot s = ks*4+quad; physical = s^(lr&7)
  const int s0  = ((quad ^ (lr & 7)) << 4);
  const int s1  = s0 ^ 64;
  const int aro = (wr * 64 + lr) << 7;
  const int bro = (wc * 32 + lr) << 7;

  bf16x8 aF[8];
  bf16x8 bF0[4], bF1[4];

  const int NT = p.K >> 6;

  // ---- prologue: tile0 (4 halves) + tile1 (A-mh0, B-nh0) ----
  stageA(0, 0, 0); stageA(0, 1, 0); stageB(0, 0, 0); stageB(0, 1, 0);
  if (NT > 1) {
    stageA(1, 0, 64); stageB(1, 0, 64);
    asm volatile("s_waitcnt vmcnt(4)" ::: "memory");
  } else {
    asm volatile("s_waitcnt vmcnt(0)" ::: "memory");
  }
  __builtin_amdgcn_s_barrier();

#pragma unroll 2
  for (int t = 0; t < NT; ++t) {
    const int d  = t & 1;
    const int k1 = (t + 1) << 6;
    const int k2 = (t + 2) << 6;

    LDA8(d, 0); LDB4(d, 0, bF0);
    if (t + 1 < NT) stageA(d ^ 1, 1, k1);
    __builtin_amdgcn_s_barrier();
    MFMA16(0, 0, bF0);

    LDB4(d, 1, bF1);
    if (t + 1 < NT) stageB(d ^ 1, 1, k1);
    __builtin_amdgcn_s_barrier();
    MFMA16(0, 1, bF1);

    LDA8(d, 1);
    if (t + 2 < NT) stageA(d, 0, k2);
    __builtin_amdgcn_s_barrier();
    MFMA16(1, 1, bF1);

    if (t + 2 < NT) {
      stageB(d, 0, k2);
      asm volatile("s_waitcnt vmcnt(4)" ::: "memory");
    } else {
      asm volatile("s_waitcnt vmcnt(0)" ::: "memory");
    }
    __builtin_amdgcn_s_barrier();
    MFMA16(1, 0, bF0);
  }

  // ---- epilogue ----  (C/D layout: col = lane&15, row = quad*4 + r)
  // After the final barrier all waves' LDS reads are consumed -> LDS free.
  if constexpr (EPI == EPI_BF16) {
    // bf16 LDS-bounce. Per-wave 16KB [128m][64n], 16B-chunk XOR swizzle by m&7.
    char* Wb = ldsc + wave * 16384;
#pragma unroll
    for (int i = 0; i < 8; ++i) {
      const int mb = (i >> 2) * 64 + (i & 3) * 16 + quad * 4;     // + r
#pragma unroll
      for (int j = 0; j < 4; ++j) {
        const int nl = (j >> 1) * 32 + (j & 1) * 16 + lr;         // 0..63
        const int gn = n0 + wc * 64 + nl;
        const float bv = (p.bias2 && gn >= 1024) ? p.bias2[gn - 1024]
                       : (p.bias ? p.bias[gn] : 0.0f);
#pragma unroll
        for (int r = 0; r < 4; ++r) {
          float v = acc[i][j][r] + bv;
          if (RELU) v = fmaxf(v, 0.0f);
          const int m = mb + r;
          const int nb = nl * 2;
          const int phys = (m << 7) + (((nb & ~15) ^ ((m & 7) << 4)) | (nb & 15));
          *(bf16_t*)(Wb + phys) = f2bf(v);
        }
      }
    }
    asm volatile("s_waitcnt lgkmcnt(0)" ::: "memory");
    bf16_t* Cb = (bf16_t*)p.C + (size_t)z * (size_t)p.sC
               + (size_t)(m0 + wr * 128) * p.ldc + (n0 + wc * 64);
#pragma unroll
    for (int q = 0; q < 16; ++q) {
      const int m = q * 8 + (lane >> 3);
      const int c = lane & 7;
      const bf16x8 vv = *(const bf16x8*)(Wb + (m << 7) + (((c ^ (m & 7)) << 4)));
      *(bf16x8*)(Cb + (size_t)m * p.ldc + c * 8) = vv;
    }
  } else {
    // f32 LDS-bounce, two half-passes of [64m][64n] f32 per wave (16KB).
    // Swizzle: col' = col ^ (((m>>2)&3)<<2) — b128-safe (flips bits 2..3).
    char* Wb = ldsc + wave * 16384;
#pragma unroll
    for (int hh = 0; hh < 2; ++hh) {
#pragma unroll
      for (int ii = 0; ii < 4; ++ii) {
        const int i = hh * 4 + ii;
        const int ml = ii * 16 + quad * 4;                        // + r
#pragma unroll
        for (int j = 0; j < 4; ++j) {
          const int nl = (j >> 1) * 32 + (j & 1) * 16 + lr;       // 0..63
          const int gn = n0 + wc * 64 + nl;
          float addv = 0.0f; int mk = 1;
          if constexpr (EPI == EPI_RESID) addv = p.bias ? p.bias[gn] : 0.0f;
          if constexpr (EPI == EPI_SCORES)
            mk = p.mask[(size_t)z * (size_t)p.sMask + gn];
#pragma unroll
          for (int r = 0; r < 4; ++r) {
            const int m = ml + r;
            float v = acc[i][j][r];
            if constexpr (EPI == EPI_SCORES) v = mk ? v * p.scale : -1e9f;
            else v += addv;
            const int nph = nl ^ (((m >> 2) & 3) << 2);
            *(float*)(Wb + m * 256 + nph * 4) = v;
          }
        }
      }
      asm volatile("s_waitcnt lgkmcnt(0)" ::: "memory");
      // coalesced pass: lane = 16 n-slots x 4 m; 16 iters cover 64 rows.
      const int mb = m0 + wr * 128 + hh * 64;
      const int gn0 = n0 + wc * 64 + lr * 4;
#pragma unroll
      for (int q = 0; q < 16; ++q) {
        const int m = q * 4 + quad;
        const int nph = (lr * 4) ^ (((m >> 2) & 3) << 2);
        f32x4 v = *(const f32x4*)(Wb + m * 256 + nph * 4);
        const size_t off = (size_t)z * (size_t)p.sC
                         + (size_t)(mb + m) * p.ldc + gn0;
        if constexpr (EPI == EPI_RESID) {
          const f32x4 rv = *(const f32x4*)(p.resid + off);
          v = v + rv;
        }
        *(f32x4*)((float*)p.C + off) = v;
      }
      // next half-pass reuses the same private 16KB; within-wave lgkm order
      // is enforced by the wait above on the following iteration's reads.
      if (hh == 0) { asm volatile("s_waitcnt lgkmcnt(0)" ::: "memory"); }
    }
  }
}

template <int EPI, bool RELU>
__global__ __launch_bounds__(512, 2)
void gemm256(GemmP p)
{
  __shared__ __align__(16) char lds_[131072];
  gemm_core<EPI, RELU>(p, blockIdx.x, lds_);
}

// merged launch: blocks [0,n1) run EPI_SCORES on p1; [n1,...) EPI_BF16 on p2.
// blockIdx->XCD is round-robin on the full grid, so each segment's internal
// XCD swizzle stays valid ((n1+i)%8 == i%8 since n1 % 8 == 0).
__global__ __launch_bounds__(512, 2)
void gemm_pair(GemmP p1, int n1, GemmP p2)
{
  __shared__ __align__(16) char lds_[131072];
  if ((int)blockIdx.x < n1) gemm_core<EPI_SCORES, false>(p1, blockIdx.x, lds_);
  else                      gemm_core<EPI_BF16,   false>(p2, blockIdx.x - n1, lds_);
}

// ---------------------------------------------------------------------------
// Shared device bodies: LayerNorm row, softmax row, 32x32 tile transpose.
// ---------------------------------------------------------------------------
__device__ __forceinline__ void ln_body(const float* __restrict__ x,
                                        const float* __restrict__ g,
                                        const float* __restrict__ b,
                                        bf16_t* __restrict__ out,
                                        int row, int t, float* red)
{
  const int wave = t >> 6, lane = t & 63;
  const float4 v = ((const float4*)(x + (size_t)row * DD))[t];

  float s = v.x + v.y + v.z + v.w;
#pragma unroll
  for (int o = 32; o > 0; o >>= 1) s += __shfl_down(s, o);
  if (lane == 0) red[wave] = s;
  __syncthreads();
  const float mu = (red[0] + red[1] + red[2] + red[3]) * (1.0f / DD);

  const float d0 = v.x - mu, d1 = v.y - mu, d2 = v.z - mu, d3 = v.w - mu;
  float ss = d0 * d0 + d1 * d1 + d2 * d2 + d3 * d3;
#pragma unroll
  for (int o = 32; o > 0; o >>= 1) ss += __shfl_down(ss, o);
  if (lane == 0) red[4 + wave] = ss;
  __syncthreads();
  const float var = (red[4] + red[5] + red[6] + red[7]) * (1.0f / DD);
  const float rs  = rsqrtf(var + 1e-5f);

  const float4 gg = ((const float4*)g)[t];
  const float4 bb = ((const float4*)b)[t];
  short4v o;
  o.x = (short)f2bf(d0 * rs * gg.x + bb.x);
  o.y = (short)f2bf(d1 * rs * gg.y + bb.y);
  o.z = (short)f2bf(d2 * rs * gg.z + bb.z);
  o.w = (short)f2bf(d3 * rs * gg.w + bb.w);
  *(short4v*)(out + (size_t)row * DD + t * 4) = o;
}

__global__ __launch_bounds__(256)
void softmax_kernel(float* __restrict__ w, bf16_t* __restrict__ wb)
{
  __shared__ float red[8];
  const size_t rowoff = (size_t)blockIdx.x * SS;
  float* p = w + rowoff;
  const int t = threadIdx.x;
  const int wave = t >> 6, lane = t & 63;
  float4 v0 = ((float4*)p)[t];
  float4 v1 = ((float4*)p)[t + 256];

  float m = fmaxf(fmaxf(fmaxf(v0.x, v0.y), fmaxf(v0.z, v0.w)),
                  fmaxf(fmaxf(v1.x, v1.y), fmaxf(v1.z, v1.w)));
#pragma unroll
  for (int o = 32; o > 0; o >>= 1) m = fmaxf(m, __shfl_down(m, o));
  if (lane == 0) red[wave] = m;
  __syncthreads();
  m = fmaxf(fmaxf(red[0], red[1]), fmaxf(red[2], red[3]));

  v0.x = __expf(v0.x - m); v0.y = __expf(v0.y - m);
  v0.z = __expf(v0.z - m); v0.w = __expf(v0.w - m);
  v1.x = __expf(v1.x - m); v1.y = __expf(v1.y - m);
  v1.z = __expf(v1.z - m); v1.w = __expf(v1.w - m);

  float s = v0.x + v0.y + v0.z + v0.w + v1.x + v1.y + v1.z + v1.w;
#pragma unroll
  for (int o = 32; o > 0; o >>= 1) s += __shfl_down(s, o);
  if (lane == 0) red[4 + wave] = s;
  __syncthreads();
  const float inv = 1.0f / (red[4] + red[5] + red[6] + red[7]);

  v0.x *= inv; v0.y *= inv; v0.z *= inv; v0.w *= inv;
  v1.x *= inv; v1.y *= inv; v1.z *= inv; v1.w *= inv;
  ((float4*)p)[t] = v0;
  ((float4*)p)[t + 256] = v1;

  short4v o0 = { (short)f2bf(v0.x), (short)f2bf(v0.y), (short)f2bf(v0.z), (short)f2bf(v0.w) };
  short4v o1 = { (short)f2bf(v1.x), (short)f2bf(v1.y), (short)f2bf(v1.z), (short)f2bf(v1.w) };
  *(short4v*)(wb + rowoff + t * 4)         = o0;
  *(short4v*)(wb + rowoff + (t + 256) * 4) = o1;
}

template <typename ST>
__device__ __forceinline__ void transpose_body(const ST* __restrict__ in,
                                               bf16_t* __restrict__ out,
                                               int R, int ldin,
                                               long long inB, long long outB,
                                               int xb, int yb, int zb,
                                               int tx, int ty, float* tile)
{
  const size_t zi = (size_t)zb * (size_t)inB;
  const size_t zo = (size_t)zb * (size_t)outB;
  const int c0 = xb * 32, r0 = yb * 32;
#pragma unroll
  for (int k = 0; k < 32; k += 8) {
    ST raw = in[zi + (size_t)(r0 + ty + k) * ldin + (c0 + tx)];
    float v;
    if constexpr (sizeof(ST) == 2) {
      v = __uint_as_float(((unsigned)(unsigned short)raw) << 16);
    } else {
      v = (float)raw;
    }
    tile[(ty + k) * 33 + tx] = v;
  }
  __syncthreads();
#pragma unroll
  for (int k = 0; k < 32; k += 8)
    out[zo + (size_t)(c0 + ty + k) * R + (r0 + tx)] = f2bf(tile[tx * 33 + ty + k]);
}

// ---------------------------------------------------------------------------
// prep: 5 weight transposes (blocks 0..5119) + LN1 rows (blocks 5120..21503)
// ---------------------------------------------------------------------------
__global__ __launch_bounds__(256)
void prep_kernel(const float* __restrict__ Wq, const float* __restrict__ Wk,
                 const float* __restrict__ Wo, const float* __restrict__ W1,
                 const float* __restrict__ W2,
                 bf16_t* __restrict__ WqkT, bf16_t* __restrict__ WoT,
                 bf16_t* __restrict__ W1T, bf16_t* __restrict__ W2T,
                 const float* __restrict__ x, const float* __restrict__ g,
                 const float* __restrict__ b, bf16_t* __restrict__ xn)
{
  __shared__ float smem[32 * 33];
  const int bid = blockIdx.x;
  const int tid = threadIdx.x;
  if (bid < 5120) {
    const int wi = bid >> 10;
    const int rem = bid & 1023;
    const float* src = wi == 0 ? Wq : wi == 1 ? Wk : wi == 2 ? Wo : wi == 3 ? W1 : W2;
    bf16_t* dst = wi == 0 ? WqkT : wi == 1 ? (WqkT + (size_t)DD * DD)
                 : wi == 2 ? WoT : wi == 3 ? W1T : W2T;
    transpose_body<float>(src, dst, DD, DD, 0, 0,
                          rem & 31, rem >> 5, 0, tid & 31, tid >> 5, smem);
  } else {
    ln_body(x, g, b, xn, bid - 5120, tid, smem);
  }
}

__global__ __launch_bounds__(256)
void ln_kernel(const float* __restrict__ x, const float* __restrict__ g,
               const float* __restrict__ b, bf16_t* __restrict__ out)
{
  __shared__ float red[8];
  ln_body(x, g, b, out, blockIdx.x, threadIdx.x, red);
}

// ---------------------------------------------------------------------------
extern "C" void kernel_launch(void* const* d_in, const int* in_sizes, int n_in,
                              void* d_out, int out_size, void* d_ws, size_t ws_size,
                              hipStream_t stream)
{
  const float* x    = (const float*)d_in[0];
  const int*   mask = (const int*)d_in[1];
  const float* ln1g = (const float*)d_in[2];
  const float* ln1b = (const float*)d_in[3];
  const float* Wq   = (const float*)d_in[4];
  const float* bq   = (const float*)d_in[5];
  const float* Wk   = (const float*)d_in[6];
  const float* bk   = (const float*)d_in[7];
  const float* Wo   = (const float*)d_in[8];
  const float* bo   = (const float*)d_in[9];
  const float* ln2g = (const float*)d_in[10];
  const float* ln2b = (const float*)d_in[11];
  const float* W1   = (const float*)d_in[12];
  const float* b1   = (const float*)d_in[13];
  const float* W2   = (const float*)d_in[14];
  const float* b2   = (const float*)d_in[15];

  float* out  = (float*)d_out;                       // (B,S,D) f32, 64MB
  float* wout = out + (size_t)BB * SS * DD;          // (B,S,S) f32, 128MB

  // ---- workspace layout, plus d_out-region reuse ----
  char* ws = (char*)d_ws;
  size_t off = 0;
  auto alloc = [&](size_t bytes) {
    char* p = ws + off; off += (bytes + 255) & ~(size_t)255; return p;
  };
  bf16_t* WqkT = (bf16_t*)alloc((size_t)2 * DD * DD * 2);   // [2048,1024] = WqT ; WkT
  bf16_t* WoT  = (bf16_t*)alloc((size_t)DD * DD * 2);
  bf16_t* W1T  = (bf16_t*)alloc((size_t)DD * DD * 2);
  bf16_t* W2T  = (bf16_t*)alloc((size_t)DD * DD * 2);
  bf16_t* QKb  = (bf16_t*)alloc((size_t)BB * SS * 2 * DD * 2);  // [16384,2048] bf16, 64MB
  char*   Rwb  = alloc((size_t)64 * 1024 * 1024);               // wbf -> xn2+h
  bf16_t* KWoT = (bf16_t*)alloc((size_t)BB * SS * DD * 2);      // (V@Wo)^T [B,1024,2048], 32MB

  bf16_t* wbf = (bf16_t*)Rwb;                      // (B,S,S) bf16, dies after w@KWo
  bf16_t* xn2 = (bf16_t*)Rwb;                      // (B*S,D) bf16 (after wbf dead)
  bf16_t* h   = (bf16_t*)(Rwb + (size_t)32 * 1024 * 1024);  // (B*S,D_FF) bf16

  // d_out reuse: xn lives in wout region (dead before scores written);
  // x2 lives in out region from the w@KWo step.
  bf16_t* xn = (bf16_t*)wout;                      // (B*S,D) bf16, dies after QK
  float*  x2 = out;                                // (B*S,D) f32

  const dim3 tb(256);
  const dim3 tg(512);
  const long long SD   = (long long)SS * DD;       // 2M elems
  const long long S2   = (long long)SS * SS;       // 4M elems
  const long long QKs  = (long long)SS * 2 * DD;   // per-batch elems in QKb

  // 1. prep: weights -> transposed bf16 [N][K] (Wq,Wk concatenated) + LN1
  prep_kernel<<<dim3(5120 + BB * SS), tb, 0, stream>>>(
      Wq, Wk, Wo, W1, W2, WqkT, WoT, W1T, W2T, x, ln1g, ln1b, xn);

  // 2. QK = xn @ [Wq|Wk] + [bq|bk]   (bf16, [16384,2048])
  gemm256<EPI_BF16, false><<<dim3(512), tg, 0, stream>>>(GemmP{
      xn, WqkT, QKb, bq, bk, nullptr, nullptr,
      64, 8, 1, 8, DD, DD, DD, 2 * DD, 0, 0, 0, 0, 1.0f});

  // 3. merged: scores = QK^T/32 masked -> wout (blocks 0..511)
  //          + KWoT = (K@Wo)^T via NT(WoT, K) -> bf16 [B,1024,2048] (512..767)
  //   (reassociation (w@V)@Wo == w@(V@Wo); V==K per reference bug)
  {
    GemmP ps{QKb, QKb + DD, wout, nullptr, nullptr, nullptr, mask,
             8, 8, BB, 8, DD, 2 * DD, 2 * DD, SS, QKs, QKs, S2, SS, 0.03125f};
    GemmP pk{WoT, QKb + DD, KWoT, nullptr, nullptr, nullptr, nullptr,
             4, 8, BB, 8, DD, DD, 2 * DD, SS, 0, QKs, SD, 0, 1.0f};
    gemm_pair<<<dim3(768), tg, 0, stream>>>(ps, 512, pk);
  }

  // 4. softmax rows -> wout (f32, required output) + wbf (bf16)
  softmax_kernel<<<dim3(BB * SS), tb, 0, stream>>>(wout, wbf);

  // 5. x2 = x + w @ KWoT^T + bo  (f32, into out region)
  gemm256<EPI_RESID, false><<<dim3(256), tg, 0, stream>>>(GemmP{
      wbf, KWoT, x2, bo, nullptr, x, nullptr,
      8, 4, BB, 4, SS, SS, SS, DD, S2, SD, SD, 0, 1.0f});

  // 6. xn2 = LN2(x2)
  ln_kernel<<<dim3(BB * SS), tb, 0, stream>>>(x2, ln2g, ln2b, xn2);

  // 7. h = relu(xn2@W1 + b1)  (bf16)
  gemm256<EPI_BF16, true><<<dim3(256), tg, 0, stream>>>(GemmP{
      xn2, W1T, h, b1, nullptr, nullptr, nullptr,
      64, 4, 1, 4, DD, DD, DD, DD, 0, 0, 0, 0, 1.0f});

  // 8. out = x2 + h@W2 + b2  (f32, elementwise RMW of out region)
  gemm256<EPI_RESID, false><<<dim3(256), tg, 0, stream>>>(GemmP{
      h, W2T, out, b2, nullptr, x2, nullptr,
      64, 4, 1, 4, DD, DD, DD, DD, 0, 0, 0, 0, 1.0f});
}